// Round 4
// baseline (2069.998 us; speedup 1.0000x reference)
//
#include <hip/hip_runtime.h>

// ---------------------------------------------------------------------------
// Spiking VGG9, 10 steps, B=128.  R4: halo-LDS conv + pipelined B staging.
//  - A (activations) staged ONCE per 64-ic slab into LDS with halo; 9 taps
//    read shifted windows (position-keyed XOR swizzle, pre-swizzled source)
//  - B (weights) streamed per (tap,split) in 8KB tiles, 3-buffer rotation,
//    raw s_barrier + counted vmcnt(2)  (no full drain in steady state)
//  - 3-way bf16 weight split (fp32-exact), spikes exact in bf16
// ---------------------------------------------------------------------------

typedef __attribute__((ext_vector_type(8))) short short8v;
typedef __attribute__((ext_vector_type(4))) float f32x4;

__device__ __forceinline__ ushort f2bf(float f) {
    union { float f; unsigned u; } v; v.f = f;
    unsigned u = v.u;
    u += 0x7fffu + ((u >> 16) & 1u);   // RNE
    return (ushort)(u >> 16);
}
__device__ __forceinline__ float bf2f(ushort h) {
    union { unsigned u; float f; } v; v.u = ((unsigned)h) << 16;
    return v.f;
}
constexpr int ilog2(int x) { int r = 0; while (x > 1) { x >>= 1; ++r; } return r; }

__device__ __forceinline__ void gl_lds16(const ushort* g, ushort* l) {
    __builtin_amdgcn_global_load_lds(
        (const __attribute__((address_space(1))) unsigned int*)g,
        (__attribute__((address_space(3))) unsigned int*)l, 16, 0, 0);
}

// ---------------------------------------------------------------- zero ----
__global__ void zero4_k(float4* __restrict__ p, int n4) {
    int i = blockIdx.x * 256 + threadIdx.x;
    if (i < n4) p[i] = make_float4(0.f, 0.f, 0.f, 0.f);
}

// ------------------------------------------------------------ weight prep --
// OIHW fp32 -> wq[slab][tap q][split s][oct][ocl 64][64k], chunk pre-swizzled
// by (ocl&7) so kernel staging is a pure linear copy.
template <int IC, int OC>
__global__ void prep_convw_k(const float* __restrict__ w, ushort* __restrict__ dst) {
    int idx = blockIdx.x * 256 + threadIdx.x;
    if (idx >= OC * IC * 9) return;
    int oc = idx / (IC * 9);
    int rem = idx % (IC * 9);
    int ic = rem / 9, q = rem % 9;
    float v = w[idx];
    ushort s0 = f2bf(v);
    float r1 = v - bf2f(s0);
    ushort s1 = f2bf(r1);
    float r2 = r1 - bf2f(s1);
    ushort s2 = f2bf(r2);
    int sg = ic >> 6, kin = ic & 63, cc = kin >> 3, ee = kin & 7;
    int oct = oc >> 6, ocl = oc & 63;
    constexpr int OCT = OC / 64;
    ushort vals[3] = {s0, s1, s2};
#pragma unroll
    for (int s = 0; s < 3; ++s)
        dst[(((((size_t)sg * 9 + q) * 3 + s) * OCT + oct) << 12)
            + (ocl << 6) + ((cc ^ (ocl & 7)) << 3) + ee] = vals[s];
}

// fc1 weights [1024][4096] fp32, cols k=(c*16+h*4+w) -> k'=(h*4+w)*256+c,
// pack [s][kb(128)][j(1024)][32]
__global__ void prep_fc1w_k(const float* __restrict__ w, ushort* __restrict__ dst) {
    int idx = blockIdx.x * 256 + threadIdx.x;
    if (idx >= 1024 * 4096) return;
    int j = idx >> 12, k = idx & 4095;
    int c = k >> 4, hw = k & 15;
    int kp = hw * 256 + c;
    float v = w[idx];
    ushort s0 = f2bf(v);
    float r1 = v - bf2f(s0);
    ushort s1 = f2bf(r1);
    float r2 = r1 - bf2f(s1);
    ushort s2 = f2bf(r2);
    constexpr size_t SS = (size_t)128 * 1024 * 32;
    size_t b = ((size_t)(kp >> 5) * 1024 + j) * 32 + (kp & 31);
    dst[b] = s0; dst[b + SS] = s1; dst[b + 2 * SS] = s2;
}

// ------------------------------------------------------------ conv1 (fp32) --
// coalesced: thread (px, q) computes 16 oc for one pixel; 64 contiguous
// floats written per pixel.
__global__ __launch_bounds__(256) void conv1_k(const float* __restrict__ inp,
                                               const float* __restrict__ w1,
                                               float* __restrict__ stat) {
    __shared__ float ws[27 * 64];
    for (int e = threadIdx.x; e < 1728; e += 256) {
        int oc = e / 27, j = e % 27;
        ws[j * 64 + oc] = w1[e];
    }
    __syncthreads();
    int t = blockIdx.x * 256 + threadIdx.x;
    int q = t & 3;
    int m = t >> 2;
    int n = m >> 10, h = (m >> 5) & 31, w = m & 31;
    float xv[27];
#pragma unroll
    for (int ic = 0; ic < 3; ++ic)
#pragma unroll
        for (int kh = 0; kh < 3; ++kh)
#pragma unroll
            for (int kw = 0; kw < 3; ++kw) {
                int r = h + kh - 1, c = w + kw - 1;
                xv[ic * 9 + kh * 3 + kw] =
                    (r >= 0 && r < 32 && c >= 0 && c < 32)
                        ? inp[(n * 3 + ic) * 1024 + r * 32 + c] : 0.0f;
            }
    float acc[16];
#pragma unroll
    for (int o = 0; o < 16; ++o) acc[o] = 0.f;
#pragma unroll
    for (int j = 0; j < 27; ++j) {
        float x = xv[j];
        const float* wr = &ws[j * 64 + q * 16];
#pragma unroll
        for (int o = 0; o < 16; ++o) acc[o] += wr[o] * x;
    }
#pragma unroll
    for (int i = 0; i < 4; ++i)
        *(float4*)&stat[(size_t)m * 64 + q * 16 + i * 4] =
            make_float4(acc[i * 4], acc[i * 4 + 1], acc[i * 4 + 2], acc[i * 4 + 3]);
}

// ---------------------------------------------------------------- LIF0 ----
__global__ void lif0_k(const float* __restrict__ stat, float* __restrict__ mem,
                       ushort* __restrict__ act1) {
    int i = blockIdx.x * 256 + threadIdx.x;   // 2,097,152 float4 units
    float4 s = ((const float4*)stat)[i];
    float4 m = ((float4*)mem)[i];
    float p0, p1, p2, p3;
    m.x = 0.05f * m.x + 0.95f * s.x; p0 = (m.x > 1.f) ? 1.f : 0.f; m.x -= p0;
    m.y = 0.05f * m.y + 0.95f * s.y; p1 = (m.y > 1.f) ? 1.f : 0.f; m.y -= p1;
    m.z = 0.05f * m.z + 0.95f * s.z; p2 = (m.z > 1.f) ? 1.f : 0.f; m.z -= p2;
    m.w = 0.05f * m.w + 0.95f * s.w; p3 = (m.w > 1.f) ? 1.f : 0.f; m.w -= p3;
    ((float4*)mem)[i] = m;
    int e = i * 4;
    int c = e & 63, w = (e >> 6) & 31, h = (e >> 11) & 31, n = e >> 16;
    size_t d = ((size_t)(n * 34 + h + 1) * 34 + (w + 1)) * 64 + c;
    short4 o;
    o.x = p0 > 0.f ? (short)0x3F80 : 0;
    o.y = p1 > 0.f ? (short)0x3F80 : 0;
    o.z = p2 > 0.f ? (short)0x3F80 : 0;
    o.w = p3 > 0.f ? (short)0x3F80 : 0;
    *(short4*)&act1[d] = o;
}

// --------------------------------------------------- implicit-GEMM conv ----
// act: padded NHWC bf16 [n][H+2][W+2][IC]; wq per prep_convw_k.
// Block: NI images x MR rows x W cols (= MBLK pixels) x 64 oc.
// EPI: 0 = spike compact, 1 = spike padded, 2 = fp32 split-K partial
template <int H, int W, int IC, int OC, int NI, int MR, int KT, int EPI>
__global__ __launch_bounds__(256) void convmm_k(const ushort* __restrict__ act,
                                                const ushort* __restrict__ wq,
                                                ushort* __restrict__ outs,
                                                float* __restrict__ outp) {
    constexpr int PW = W + 2, PHR = MR + 2;
    constexpr int MBLK = NI * MR * W;
    constexpr int WM = MBLK / 2;
    constexpr int AM = WM / 16;
    constexpr int ICP = IC / 64;
    constexpr int SLABS = ICP / KT;
    constexpr int OCT = OC / 64;
    constexpr int HCH = NI * PHR * PW * 8;        // halo 16B chunks
    constexpr int HR = (HCH + 255) / 256;
    constexpr int LHW = ilog2(H * W), LW2 = ilog2(W);
    constexpr int LMW = ilog2(MR * W);

    __shared__ __align__(16) ushort sA[NI * PHR * PW * 64];
    __shared__ __align__(16) ushort sB[3][4096];

    const int tid = threadIdx.x, lane = tid & 63;
    const int wid = tid >> 6, wm = wid >> 1, wn = wid & 1;
    const int b = blockIdx.x;
    const int oct = blockIdx.y, oc0 = oct * 64;
    const int kt = blockIdx.z;
    const int m0 = b * MBLK;
    constexpr int TPI = (NI == 1) ? (H / MR) : 1;
    const int n0 = (NI == 1) ? (b / TPI) : (b * NI);
    const int h0 = (NI == 1) ? (b % TPI) * MR : 0;

    // A-fragment bases (per am): halo row base + in-row col
    int rowb[AM], wv[AM];
#pragma unroll
    for (int am = 0; am < AM; ++am) {
        int p = wm * WM + am * 16 + (lane & 15);
        int img = p >> LMW;
        int pi = p & ((MR * W) - 1);
        int h = pi >> LW2;
        rowb[am] = (img * PHR + h) * PW;
        wv[am] = pi & (W - 1);
    }

    auto stage_B = [&](int sg_, int q_, int s_, int buf_) {
        const ushort* src = wq + ((((size_t)(sg_ * 9 + q_) * 3 + s_) * OCT + oct) << 12) + (tid << 3);
        gl_lds16(src, &sB[buf_][tid * 8]);
        gl_lds16(src + 2048, &sB[buf_][2048 + tid * 8]);
    };
    auto stage_halo = [&](int sg_) {
#pragma unroll
        for (int r = 0; r < HR; ++r) {
            int i = r * 256 + tid;
            if (i < HCH) {
                int e = i & 7;
                int pix = i >> 3;
                int pc = pix % PW;
                int t2 = pix / PW;
                int hp = t2 % PHR;
                int img = t2 / PHR;
                const ushort* src = act
                    + (((size_t)(n0 + img) * (H + 2) + h0 + hp) * PW + pc) * IC
                    + (sg_ << 6) + ((e ^ (pc & 7)) << 3);
                gl_lds16(src, &sA[(size_t)i * 8]);
            }
        }
    };

    f32x4 acc[AM][2];
#pragma unroll
    for (int a = 0; a < AM; ++a) {
        acc[a][0] = (f32x4){0.f, 0.f, 0.f, 0.f};
        acc[a][1] = (f32x4){0.f, 0.f, 0.f, 0.f};
    }

    for (int sl = 0; sl < SLABS; ++sl) {
        const int sg = kt * SLABS + sl;
        // prior slab's compute finished at its last barrier
        stage_halo(sg);
        stage_B(sg, 0, 0, 0);
        stage_B(sg, 0, 1, 1);
        asm volatile("s_waitcnt vmcnt(2)" ::: "memory");   // halo + B(0,0) landed
        __builtin_amdgcn_s_barrier();
        __builtin_amdgcn_sched_barrier(0);

        for (int q = 0; q < 9; ++q) {
            const int qr = q / 3, qc = q % 3;
            // A fragments for this tap (sA is stable; swizzle key = padded col)
            short8v af[2][AM];
#pragma unroll
            for (int kh = 0; kh < 2; ++kh)
#pragma unroll
                for (int am = 0; am < AM; ++am) {
                    int wp = wv[am] + qc;
                    int addr = (rowb[am] + qr * PW + wp) * 64
                             + ((((kh << 2) | (lane >> 4)) ^ (wp & 7)) << 3);
                    af[kh][am] = *(const short8v*)&sA[addr];
                }
#pragma unroll
            for (int s = 0; s < 3; ++s) {
#pragma unroll
                for (int kh = 0; kh < 2; ++kh) {
                    const int ck = (kh << 2) | (lane >> 4);
                    short8v b0, b1;
                    {
                        int R = wn * 32 + (lane & 15);
                        b0 = *(const short8v*)&sB[s][(R << 6) + ((ck ^ (R & 7)) << 3)];
                    }
                    {
                        int R = wn * 32 + 16 + (lane & 15);
                        b1 = *(const short8v*)&sB[s][(R << 6) + ((ck ^ (R & 7)) << 3)];
                    }
#pragma unroll
                    for (int am = 0; am < AM; ++am) {
                        acc[am][0] = __builtin_amdgcn_mfma_f32_16x16x32_bf16(
                            af[kh][am], b0, acc[am][0], 0, 0, 0);
                        acc[am][1] = __builtin_amdgcn_mfma_f32_16x16x32_bf16(
                            af[kh][am], b1, acc[am][1], 0, 0, 0);
                    }
                }
                // pipeline: issue stage for unit u+2 (3-buffer rotation)
                const int nq = (s == 0) ? q : q + 1;
                const int ns = (s + 2) % 3;
                if (nq <= 8) {
                    stage_B(sg, nq, ns, ns);
                    asm volatile("s_waitcnt vmcnt(2)" ::: "memory");
                } else {
                    asm volatile("s_waitcnt vmcnt(0)" ::: "memory");
                }
                __builtin_amdgcn_s_barrier();
                __builtin_amdgcn_sched_barrier(0);
            }
        }
    }

    constexpr size_t MTOT = (size_t)128 * H * W;
#pragma unroll
    for (int am = 0; am < AM; ++am)
#pragma unroll
        for (int bn = 0; bn < 2; ++bn)
#pragma unroll
            for (int rr = 0; rr < 4; ++rr) {
                int rl = wm * WM + am * 16 + (lane >> 4) * 4 + rr;
                int col = oc0 + wn * 32 + bn * 16 + (lane & 15);
                int m = m0 + rl;
                float v = acc[am][bn][rr];
                if (EPI == 2) {
                    outp[((size_t)kt * MTOT + m) * OC + col] = v;
                } else {
                    ushort sp = (v > 1.0f) ? (ushort)0x3F80 : (ushort)0;
                    if (EPI == 1) {
                        int n = m >> LHW, h = (m >> LW2) & (H - 1), w = m & (W - 1);
                        outs[((size_t)(n * (H + 2) + h + 1) * PW + (w + 1)) * OC + col] = sp;
                    } else {
                        outs[(size_t)m * OC + col] = sp;
                    }
                }
            }
}

// ---------------------------------------------- split-K combine (+spike) ----
template <int H, int OC>
__global__ void combine_k(const float* __restrict__ part, ushort* __restrict__ out) {
    constexpr size_t MTOT = (size_t)128 * H * H;
    constexpr size_t TOT = MTOT * OC;
    constexpr int LH = ilog2(H);
    size_t i = ((size_t)blockIdx.x * 256 + threadIdx.x) * 4;
    if (i >= TOT) return;
    float4 a = *(const float4*)&part[i];
    float4 b = *(const float4*)&part[TOT + i];
    short4 o;
    o.x = (a.x + b.x > 1.f) ? (short)0x3F80 : 0;
    o.y = (a.y + b.y > 1.f) ? (short)0x3F80 : 0;
    o.z = (a.z + b.z > 1.f) ? (short)0x3F80 : 0;
    o.w = (a.w + b.w > 1.f) ? (short)0x3F80 : 0;
    int m = (int)(i / OC), c = (int)(i % OC);
    int n = m >> (2 * LH), h = (m >> LH) & (H - 1), w = m & (H - 1);
    *(short4*)&out[((size_t)(n * (H + 2) + h + 1) * (H + 2) + (w + 1)) * OC + c] = o;
}

// conv7 combine fused with 2x2 avgpool -> afc1 [128][4][4][256] bf16
__global__ void comb7pool_k(const float* __restrict__ part, ushort* __restrict__ out) {
    int idx = blockIdx.x * 256 + threadIdx.x;   // 131072
    int c4 = idx & 63;
    int t = idx >> 6;
    int wo = t & 3, ho = (t >> 2) & 3, n = t >> 4;
    int c = c4 * 4;
    float4 s = {0.f, 0.f, 0.f, 0.f};
#pragma unroll
    for (int dh = 0; dh < 2; ++dh)
#pragma unroll
        for (int dw = 0; dw < 2; ++dw) {
            int m = (n * 8 + 2 * ho + dh) * 8 + 2 * wo + dw;
            float4 a = *(const float4*)&part[(size_t)m * 256 + c];
            float4 b = *(const float4*)&part[(size_t)(8192 + m) * 256 + c];
            s.x += (a.x + b.x > 1.f) ? 1.f : 0.f;
            s.y += (a.y + b.y > 1.f) ? 1.f : 0.f;
            s.z += (a.z + b.z > 1.f) ? 1.f : 0.f;
            s.w += (a.w + b.w > 1.f) ? 1.f : 0.f;
        }
    short4 o;
    o.x = (short)f2bf(s.x * 0.25f);
    o.y = (short)f2bf(s.y * 0.25f);
    o.z = (short)f2bf(s.z * 0.25f);
    o.w = (short)f2bf(s.w * 0.25f);
    *(short4*)&out[(size_t)idx * 4] = o;
}

// ---------------------------------------------------------------- pool ----
template <int C, int HI, bool PADO>
__global__ void pool_k(const ushort* __restrict__ in, ushort* __restrict__ out) {
    constexpr int HO = HI / 2, C8 = C / 8;
    constexpr int TOT = 128 * HO * HO * C8;
    int idx = blockIdx.x * 256 + threadIdx.x;
    if (idx >= TOT) return;
    int c8 = idx % C8;
    int t = idx / C8;
    int w = t % HO; t /= HO;
    int h = t % HO;
    int n = t / HO;
    const ushort* p = in + ((size_t)(n * HI + 2 * h) * HI + 2 * w) * C + c8 * 8;
    short8v v00 = *(const short8v*)p;
    short8v v01 = *(const short8v*)(p + C);
    short8v v10 = *(const short8v*)(p + (size_t)HI * C);
    short8v v11 = *(const short8v*)(p + (size_t)HI * C + C);
    short8v r;
#pragma unroll
    for (int e = 0; e < 8; ++e) {
        float s = bf2f((ushort)v00[e]) + bf2f((ushort)v01[e]) +
                  bf2f((ushort)v10[e]) + bf2f((ushort)v11[e]);
        r[e] = (short)f2bf(s * 0.25f);
    }
    size_t a = PADO
        ? ((size_t)(n * (HO + 2) + h + 1) * (HO + 2) + (w + 1)) * C + c8 * 8
        : (size_t)idx * 8;
    *(short8v*)&out[a] = r;
}

// ----------------------------------------------------------- fc1 GEMM ----
__global__ __launch_bounds__(256) void fc1mm_k(const ushort* __restrict__ A,
                                               const ushort* __restrict__ wp,
                                               float* __restrict__ part) {
    constexpr int LW = 40;
    __shared__ ushort sA[128 * LW];
    __shared__ ushort sB[64 * LW];
    const int tid = threadIdx.x, lane = tid & 63, wid = tid >> 6;
    const int wm = wid >> 1, wn = wid & 1;
    const int j0 = blockIdx.x * 64, kt = blockIdx.y;

    int rbase[2], ldsA[2];
#pragma unroll
    for (int i = 0; i < 2; ++i) {
        int idx = i * 256 + tid;
        int r = idx >> 2, c = idx & 3;
        rbase[i] = r * 4096 + c * 8;
        ldsA[i] = r * LW + c * 8;
    }
    const int ocl = tid >> 2, cB = tid & 3;
    const int ldsBo = ocl * LW + cB * 8;

    f32x4 acc[4][2];
#pragma unroll
    for (int a = 0; a < 4; ++a) {
        acc[a][0] = (f32x4){0.f, 0.f, 0.f, 0.f};
        acc[a][1] = (f32x4){0.f, 0.f, 0.f, 0.f};
    }

    for (int st = 0; st < 12; ++st) {
        int k0 = kt * 384 + st * 32;
        int s = k0 >> 12, kk = k0 & 4095;
        __syncthreads();
#pragma unroll
        for (int i = 0; i < 2; ++i)
            *(short8v*)&sA[ldsA[i]] = *(const short8v*)&A[rbase[i] + kk];
        *(short8v*)&sB[ldsBo] =
            *(const short8v*)&wp[(((size_t)s * 128 + (kk >> 5)) * 1024 + j0 + ocl) * 32 + cB * 8];
        __syncthreads();
        short8v af[4];
#pragma unroll
        for (int am = 0; am < 4; ++am)
            af[am] = *(const short8v*)&sA[(wm * 64 + am * 16 + (lane & 15)) * LW + (lane >> 4) * 8];
        short8v b0 = *(const short8v*)&sB[(wn * 32 + (lane & 15)) * LW + (lane >> 4) * 8];
        short8v b1 = *(const short8v*)&sB[(wn * 32 + 16 + (lane & 15)) * LW + (lane >> 4) * 8];
#pragma unroll
        for (int am = 0; am < 4; ++am) {
            acc[am][0] = __builtin_amdgcn_mfma_f32_16x16x32_bf16(af[am], b0, acc[am][0], 0, 0, 0);
            acc[am][1] = __builtin_amdgcn_mfma_f32_16x16x32_bf16(af[am], b1, acc[am][1], 0, 0, 0);
        }
    }
#pragma unroll
    for (int am = 0; am < 4; ++am)
#pragma unroll
        for (int bn = 0; bn < 2; ++bn)
#pragma unroll
            for (int rr = 0; rr < 4; ++rr) {
                int row = wm * 64 + am * 16 + (lane >> 4) * 4 + rr;
                int col = j0 + wn * 32 + bn * 16 + (lane & 15);
                part[((size_t)kt * 128 + row) * 1024 + col] = acc[am][bn][rr];
            }
}

__global__ void fc1red_k(const float* __restrict__ part, float* __restrict__ mem,
                         ushort* __restrict__ sbuf) {
    int idx = blockIdx.x * 256 + threadIdx.x;   // 131072
    float y = 0.f;
#pragma unroll
    for (int kt = 0; kt < 32; ++kt) y += part[(size_t)kt * 131072 + idx];
    float m = mem[idx];
    m = 0.05f * m + 0.95f * y;
    float sp = (m > 1.f) ? 1.f : 0.f;
    m -= sp;
    mem[idx] = m;
    sbuf[idx] = sp > 0.f ? (ushort)0x3F80 : (ushort)0;
}

__global__ __launch_bounds__(256) void fc2_k(const ushort* __restrict__ S,
                                             const float* __restrict__ W2,
                                             float* __restrict__ memfc2) {
    int n = blockIdx.x, tid = threadIdx.x;
    __shared__ float red[10][256];
    const ushort* sp = S + (size_t)n * 1024 + tid * 4;
    float s0 = bf2f(sp[0]), s1 = bf2f(sp[1]), s2 = bf2f(sp[2]), s3 = bf2f(sp[3]);
#pragma unroll
    for (int o = 0; o < 10; ++o) {
        const float* w = W2 + (size_t)o * 1024 + tid * 4;
        red[o][tid] = s0 * w[0] + s1 * w[1] + s2 * w[2] + s3 * w[3];
    }
    __syncthreads();
    for (int off = 128; off >= 1; off >>= 1) {
        if (tid < off) {
#pragma unroll
            for (int o = 0; o < 10; ++o) red[o][tid] += red[o][tid + off];
        }
        __syncthreads();
    }
    if (tid < 10) memfc2[n * 10 + tid] += red[tid][0];
}

__global__ void finalize_k(const float* __restrict__ memfc2, float* __restrict__ out, int n) {
    int i = blockIdx.x * blockDim.x + threadIdx.x;
    if (i < n) out[i] = memfc2[i] * 0.1f;
}

// ---------------------------------------------------------------------------
extern "C" void kernel_launch(void* const* d_in, const int* in_sizes, int n_in,
                              void* d_out, int out_size, void* d_ws, size_t ws_size,
                              hipStream_t stream) {
    const float* inp  = (const float*)d_in[0];
    const float* w1   = (const float*)d_in[1];
    const float* w2   = (const float*)d_in[2];
    const float* w3   = (const float*)d_in[3];
    const float* w4   = (const float*)d_in[4];
    const float* w5   = (const float*)d_in[5];
    const float* w6   = (const float*)d_in[6];
    const float* w7   = (const float*)d_in[7];
    const float* fc1w = (const float*)d_in[8];
    const float* fc2w = (const float*)d_in[9];
    float* out = (float*)d_out;

    char* base = (char*)d_ws;
    size_t o = 0;
    auto alloc = [&](size_t bytes) { void* p = base + o; o += (bytes + 255) & ~(size_t)255; return p; };

    // ---- zeroed region (membranes + padded spike buffers with halos) ----
    float*  mem0  = (float*)alloc(33554432);     // [128][32][32][64] f32 NHWC
    float*  memf1 = (float*)alloc(524288);       // [128][1024] f32
    float*  memf2 = (float*)alloc(5120);         // [128][10] f32
    ushort* act1  = (ushort*)alloc(18939904);    // [128][34][34][64]
    ushort* act2  = (ushort*)alloc(5308416);     // [128][18][18][64]
    ushort* c3out = (ushort*)alloc(10616832);    // [128][18][18][128]
    ushort* act3  = (ushort*)alloc(3276800);     // [128][10][10][128]
    ushort* c5out = (ushort*)alloc(6553600);     // [128][10][10][256]
    ushort* c6out = (ushort*)alloc(6553600);     // [128][10][10][256]
    const size_t zero_bytes = 85332992;          // mem0 .. c6out inclusive
    // ---- non-zeroed ----
    float*  stat  = (float*)alloc(33554432);     // conv1 out, NHWC f32
    char*   bufC  = (char*)alloc(16777216);      // conv2/4 spikes | split-K partials | fc1 partials
    ushort* afc1  = (ushort*)alloc(1048576);     // [128][4][4][256] bf16
    ushort* sbuf  = (ushort*)alloc(262144);      // [128][1024] bf16
    ushort* wq2   = (ushort*)alloc(221184);
    ushort* wq3   = (ushort*)alloc(442368);
    ushort* wq4   = (ushort*)alloc(884736);
    ushort* wq5   = (ushort*)alloc(1769472);
    ushort* wq6   = (ushort*)alloc(3538944);
    ushort* wq7   = (ushort*)alloc(3538944);
    ushort* wpf1  = (ushort*)alloc(25165824);
    (void)ws_size;

    {
        int n4 = (int)(zero_bytes / 16);
        zero4_k<<<(n4 + 255) / 256, 256, 0, stream>>>((float4*)mem0, n4);
    }
    prep_convw_k<64, 64>  <<<(36864 + 255) / 256, 256, 0, stream>>>(w2, wq2);
    prep_convw_k<64, 128> <<<(73728 + 255) / 256, 256, 0, stream>>>(w3, wq3);
    prep_convw_k<128, 128><<<(147456 + 255) / 256, 256, 0, stream>>>(w4, wq4);
    prep_convw_k<128, 256><<<(294912 + 255) / 256, 256, 0, stream>>>(w5, wq5);
    prep_convw_k<256, 256><<<(589824 + 255) / 256, 256, 0, stream>>>(w6, wq6);
    prep_convw_k<256, 256><<<(589824 + 255) / 256, 256, 0, stream>>>(w7, wq7);
    prep_fc1w_k<<<(4194304 + 255) / 256, 256, 0, stream>>>(fc1w, wpf1);

    conv1_k<<<2048, 256, 0, stream>>>(inp, w1, stat);

    for (int t = 0; t < 10; ++t) {
        lif0_k<<<8192, 256, 0, stream>>>(stat, mem0, act1);

        convmm_k<32, 32, 64, 64, 1, 8, 1, 0>
            <<<dim3(512, 1, 1), 256, 0, stream>>>(act1, wq2, (ushort*)bufC, nullptr);
        pool_k<64, 32, true><<<1024, 256, 0, stream>>>((ushort*)bufC, act2);

        convmm_k<16, 16, 64, 128, 1, 8, 1, 1>
            <<<dim3(256, 2, 1), 256, 0, stream>>>(act2, wq3, c3out, nullptr);
        convmm_k<16, 16, 128, 128, 1, 8, 1, 0>
            <<<dim3(256, 2, 1), 256, 0, stream>>>(c3out, wq4, (ushort*)bufC, nullptr);
        pool_k<128, 16, true><<<512, 256, 0, stream>>>((ushort*)bufC, act3);

        convmm_k<8, 8, 128, 256, 2, 8, 2, 2>
            <<<dim3(64, 4, 2), 256, 0, stream>>>(act3, wq5, nullptr, (float*)bufC);
        combine_k<8, 256><<<2048, 256, 0, stream>>>((const float*)bufC, c5out);
        convmm_k<8, 8, 256, 256, 2, 8, 2, 2>
            <<<dim3(64, 4, 2), 256, 0, stream>>>(c5out, wq6, nullptr, (float*)bufC);
        combine_k<8, 256><<<2048, 256, 0, stream>>>((const float*)bufC, c6out);
        convmm_k<8, 8, 256, 256, 2, 8, 2, 2>
            <<<dim3(64, 4, 2), 256, 0, stream>>>(c6out, wq7, nullptr, (float*)bufC);
        comb7pool_k<<<512, 256, 0, stream>>>((const float*)bufC, afc1);

        fc1mm_k<<<dim3(16, 32), 256, 0, stream>>>(afc1, wpf1, (float*)bufC);
        fc1red_k<<<512, 256, 0, stream>>>((const float*)bufC, memf1, sbuf);
        fc2_k<<<128, 256, 0, stream>>>(sbuf, fc2w, memf2);
    }

    finalize_k<<<(1280 + 255) / 256, 256, 0, stream>>>(memf2, out, 1280);
}

// Round 5
// 1595.509 us; speedup vs baseline: 1.2974x; 1.2974x over previous
//
#include <hip/hip_runtime.h>

// ---------------------------------------------------------------------------
// Spiking VGG9, 10 steps, B=128.  R5: integer conv path.
//  - activations i8 (spikes {0,1}; pooled = ints 0..4, scale 1/4 folded out)
//  - weights: 3 balanced i8 digits on 2^-21 grid (w = (a0*65536+a1*256+a2)*s)
//    -> products + i32 MFMA accumulation EXACT; one fp32 fold in epilogue
//  - mfma_i32_16x16x64_i8: 2x K per instruction vs bf16 -> half the MFMA
//  - chunk-major LDS ([kchunk][pixel][16B]) -> 2-way (free) ds_read_b128,
//    no swizzle; halo staged once per 64-ic slab; B double-buffered per tap
//  - fc1 (bf16 3-split), fc2, conv1, LIF fp32 paths unchanged
// ---------------------------------------------------------------------------

typedef __attribute__((ext_vector_type(8))) short short8v;
typedef __attribute__((ext_vector_type(4))) float f32x4;
typedef __attribute__((ext_vector_type(4))) int int32x4;

__device__ __forceinline__ ushort f2bf(float f) {
    union { float f; unsigned u; } v; v.f = f;
    unsigned u = v.u;
    u += 0x7fffu + ((u >> 16) & 1u);   // RNE
    return (ushort)(u >> 16);
}
__device__ __forceinline__ float bf2f(ushort h) {
    union { unsigned u; float f; } v; v.u = ((unsigned)h) << 16;
    return v.f;
}
constexpr int ilog2(int x) { int r = 0; while (x > 1) { x >>= 1; ++r; } return r; }

__device__ __forceinline__ void gl_lds16(const void* g, void* l) {
    __builtin_amdgcn_global_load_lds(
        (const __attribute__((address_space(1))) unsigned int*)g,
        (__attribute__((address_space(3))) unsigned int*)l, 16, 0, 0);
}

#define SC21 4.76837158203125e-07f    // 2^-21  (input spikes {0,1})
#define SC23 1.1920928955078125e-07f  // 2^-23  (input ints 0..4 = 4*act)

// ---------------------------------------------------------------- zero ----
__global__ void zero4_k(float4* __restrict__ p, int n4) {
    int i = blockIdx.x * 256 + threadIdx.x;
    if (i < n4) p[i] = make_float4(0.f, 0.f, 0.f, 0.f);
}

// ------------------------------------------------------------ weight prep --
// OIHW fp32 -> 3 balanced i8 digits, layout [slab][q][oct][chunk c(4)][R(192)][16]
// where R = s*64 + ocl, chunk c covers ic kin = c*16..c*16+15.
template <int IC, int OC>
__global__ void prep_convw_i8_k(const float* __restrict__ w, char* __restrict__ dst) {
    int idx = blockIdx.x * 256 + threadIdx.x;
    if (idx >= OC * IC * 9) return;
    int oc = idx / (IC * 9);
    int rem = idx % (IC * 9);
    int ic = rem / 9, q = rem % 9;
    int wq_ = (int)rintf(w[idx] * 2097152.0f);   // 2^21 grid
    int a2 = ((wq_ + 128) & 255) - 128;
    int t2 = (wq_ - a2) >> 8;
    int a1 = ((t2 + 128) & 255) - 128;
    int a0 = (t2 - a1) >> 8;                      // |a0| small (<~20)
    int sg = ic >> 6, kin = ic & 63, c = kin >> 4, bb = kin & 15;
    int oct = oc >> 6, ocl = oc & 63;
    constexpr int OCT = OC / 64;
    size_t base = ((size_t)(sg * 9 + q) * OCT + oct) * 12288;
    char digs[3] = {(char)a0, (char)a1, (char)a2};
#pragma unroll
    for (int s = 0; s < 3; ++s)
        dst[base + (size_t)(c * 192 + s * 64 + ocl) * 16 + bb] = digs[s];
}

// fc1 weights [1024][4096] fp32, cols k=(c*16+h*4+w) -> k'=(h*4+w)*256+c,
// pack [s][kb(128)][j(1024)][32]  (bf16 3-split)
__global__ void prep_fc1w_k(const float* __restrict__ w, ushort* __restrict__ dst) {
    int idx = blockIdx.x * 256 + threadIdx.x;
    if (idx >= 1024 * 4096) return;
    int j = idx >> 12, k = idx & 4095;
    int c = k >> 4, hw = k & 15;
    int kp = hw * 256 + c;
    float v = w[idx];
    ushort s0 = f2bf(v);
    float r1 = v - bf2f(s0);
    ushort s1 = f2bf(r1);
    float r2 = r1 - bf2f(s1);
    ushort s2 = f2bf(r2);
    constexpr size_t SS = (size_t)128 * 1024 * 32;
    size_t b = ((size_t)(kp >> 5) * 1024 + j) * 32 + (kp & 31);
    dst[b] = s0; dst[b + SS] = s1; dst[b + 2 * SS] = s2;
}

// ------------------------------------------------------------ conv1 (fp32) --
__global__ __launch_bounds__(256) void conv1_k(const float* __restrict__ inp,
                                               const float* __restrict__ w1,
                                               float* __restrict__ stat) {
    __shared__ float ws[27 * 64];
    for (int e = threadIdx.x; e < 1728; e += 256) {
        int oc = e / 27, j = e % 27;
        ws[j * 64 + oc] = w1[e];
    }
    __syncthreads();
    int t = blockIdx.x * 256 + threadIdx.x;
    int q = t & 3;
    int m = t >> 2;
    int n = m >> 10, h = (m >> 5) & 31, w = m & 31;
    float xv[27];
#pragma unroll
    for (int ic = 0; ic < 3; ++ic)
#pragma unroll
        for (int kh = 0; kh < 3; ++kh)
#pragma unroll
            for (int kw = 0; kw < 3; ++kw) {
                int r = h + kh - 1, c = w + kw - 1;
                xv[ic * 9 + kh * 3 + kw] =
                    (r >= 0 && r < 32 && c >= 0 && c < 32)
                        ? inp[(n * 3 + ic) * 1024 + r * 32 + c] : 0.0f;
            }
    float acc[16];
#pragma unroll
    for (int o = 0; o < 16; ++o) acc[o] = 0.f;
#pragma unroll
    for (int j = 0; j < 27; ++j) {
        float x = xv[j];
        const float* wr = &ws[j * 64 + q * 16];
#pragma unroll
        for (int o = 0; o < 16; ++o) acc[o] += wr[o] * x;
    }
#pragma unroll
    for (int i = 0; i < 4; ++i)
        *(float4*)&stat[(size_t)m * 64 + q * 16 + i * 4] =
            make_float4(acc[i * 4], acc[i * 4 + 1], acc[i * 4 + 2], acc[i * 4 + 3]);
}

// ---------------------------------------------------------------- LIF0 ----
// spikes -> padded i8 act1 interior
__global__ void lif0_k(const float* __restrict__ stat, float* __restrict__ mem,
                       char* __restrict__ act1) {
    int i = blockIdx.x * 256 + threadIdx.x;   // 2,097,152 float4 units
    float4 s = ((const float4*)stat)[i];
    float4 m = ((float4*)mem)[i];
    float p0, p1, p2, p3;
    m.x = 0.05f * m.x + 0.95f * s.x; p0 = (m.x > 1.f) ? 1.f : 0.f; m.x -= p0;
    m.y = 0.05f * m.y + 0.95f * s.y; p1 = (m.y > 1.f) ? 1.f : 0.f; m.y -= p1;
    m.z = 0.05f * m.z + 0.95f * s.z; p2 = (m.z > 1.f) ? 1.f : 0.f; m.z -= p2;
    m.w = 0.05f * m.w + 0.95f * s.w; p3 = (m.w > 1.f) ? 1.f : 0.f; m.w -= p3;
    ((float4*)mem)[i] = m;
    int e = i * 4;
    int c = e & 63, w = (e >> 6) & 31, h = (e >> 11) & 31, n = e >> 16;
    size_t d = ((size_t)(n * 34 + h + 1) * 34 + (w + 1)) * 64 + c;
    unsigned u = (p0 > 0.f ? 1u : 0u) | (p1 > 0.f ? 1u : 0u) << 8 |
                 (p2 > 0.f ? 1u : 0u) << 16 | (p3 > 0.f ? 1u : 0u) << 24;
    *(unsigned*)&act1[d] = u;
}

// --------------------------------------------------- i8 implicit-GEMM conv --
// act: padded NHWC i8 [n][H+2][W+2][IC]; wq per prep_convw_i8_k.
// Block tile: 128 pixels x 64 oc, 4 waves (2x2), wave 64x32, AM=4 BN=2.
// EPI: 0 = spike compact, 1 = spike padded, 2 = fp32 split-K partial
template <int H, int W, int IC, int OC, int NI, int MR, int KT, int EPI>
__global__ __launch_bounds__(256) void convi8_k(const char* __restrict__ act,
                                                const char* __restrict__ wq,
                                                char* __restrict__ outs,
                                                float* __restrict__ outp,
                                                float scale) {
    constexpr int PW = W + 2, PHR = MR + 2;
    constexpr int MBLK = NI * MR * W;
    constexpr int NPIX = NI * PHR * PW;
    constexpr int ACH = NPIX * 4;                 // 16B halo chunks
    constexpr int HR = (ACH + 255) / 256;
    constexpr int SLABS = (IC / 64) / KT;
    constexpr int OCT = OC / 64;
    constexpr int LHW = ilog2(H * W), LW2 = ilog2(W), LMW = ilog2(MR * W);
    static_assert(MBLK == 128, "tile mapping");

    __shared__ __align__(16) char sA[NPIX * 64];
    __shared__ __align__(16) char sB[2][12288];

    const int tid = threadIdx.x, lane = tid & 63;
    const int wid = tid >> 6, wm = wid >> 1, wn = wid & 1;
    const int b = blockIdx.x, oct = blockIdx.y, kt = blockIdx.z;
    const int oc0 = oct * 64;
    const int m0 = b * MBLK;
    constexpr int TPI = (NI == 1) ? (H / MR) : 1;
    const int n0 = (NI == 1) ? (b / TPI) : (b * NI);
    const int h0 = (NI == 1) ? (b % TPI) * MR : 0;

    // A staging precompute (chunk-major LDS: slot idx = c*NPIX + pix)
    int asrc[HR]; bool apred[HR];
#pragma unroll
    for (int r = 0; r < HR; ++r) {
        int i = r * 256 + tid;
        apred[r] = (i < ACH);
        int ii = apred[r] ? i : 0;
        int c = ii / NPIX, pix = ii % NPIX;
        int pc = pix % PW, t2 = pix / PW;
        int hp = t2 % PHR, img = t2 / PHR;
        asrc[r] = (((n0 + img) * (H + 2) + h0 + hp) * PW + pc) * IC + c * 16;
    }
    // A fragment pixel bases
    int apix[4];
#pragma unroll
    for (int am = 0; am < 4; ++am) {
        int p = wm * 64 + am * 16 + (lane & 15);
        int img = p >> LMW;
        int pi = p & ((MR * W) - 1);
        int h = pi >> LW2;
        apix[am] = (img * PHR + h) * PW + (pi & (W - 1));
    }
    const int cA = lane >> 4;

    int32x4 acc[3][4][2];
#pragma unroll
    for (int s = 0; s < 3; ++s)
#pragma unroll
        for (int a = 0; a < 4; ++a)
#pragma unroll
            for (int bn = 0; bn < 2; ++bn) acc[s][a][bn] = (int32x4){0, 0, 0, 0};

    const size_t wqoct = (size_t)oct * 12288;
    int buf = 0;
    {   // prologue: halo(slab0) + B(slab0, q=0)
        const int sg = kt * SLABS;
#pragma unroll
        for (int r = 0; r < HR; ++r)
            if (apred[r]) gl_lds16(act + asrc[r] + sg * 64, sA + (r * 256 + tid) * 16);
        const char* wsrc = wq + (size_t)(sg * 9) * OCT * 12288 + wqoct + tid * 16;
#pragma unroll
        for (int r = 0; r < 3; ++r)
            gl_lds16(wsrc + r * 4096, sB[0] + (r * 256 + tid) * 16);
    }
    __syncthreads();

    for (int sl = 0; sl < SLABS; ++sl) {
        const int sg = kt * SLABS + sl;
        for (int q = 0; q < 9; ++q) {
            if (q < 8) {   // stage next tap's 3-split B tile into other buffer
                const char* wsrc = wq + (size_t)(sg * 9 + q + 1) * OCT * 12288 + wqoct + tid * 16;
#pragma unroll
                for (int r = 0; r < 3; ++r)
                    gl_lds16(wsrc + r * 4096, sB[buf ^ 1] + (r * 256 + tid) * 16);
            }
            const int qr = q / 3, qc = q % 3;
            int32x4 af[4];
#pragma unroll
            for (int am = 0; am < 4; ++am) {
                int pix = apix[am] + qr * PW + qc;
                af[am] = *(const int32x4*)&sA[(cA * NPIX + pix) * 16];
            }
#pragma unroll
            for (int s = 0; s < 3; ++s)
#pragma unroll
                for (int bn = 0; bn < 2; ++bn) {
                    int R = s * 64 + wn * 32 + bn * 16 + (lane & 15);
                    int32x4 bf = *(const int32x4*)&sB[buf][(cA * 192 + R) * 16];
#pragma unroll
                    for (int am = 0; am < 4; ++am)
                        acc[s][am][bn] = __builtin_amdgcn_mfma_i32_16x16x64_i8(
                            af[am], bf, acc[s][am][bn], 0, 0, 0);
                }
            if (q < 8) {
                __syncthreads();   // drains stage loads; protects buffer swap
                buf ^= 1;
            }
        }
        if (sl + 1 < SLABS) {      // slab boundary: restage halo + first B
            const int sg2 = sg + 1;
            __syncthreads();       // all waves done reading sA
#pragma unroll
            for (int r = 0; r < HR; ++r)
                if (apred[r]) gl_lds16(act + asrc[r] + sg2 * 64, sA + (r * 256 + tid) * 16);
            const char* wsrc = wq + (size_t)(sg2 * 9) * OCT * 12288 + wqoct + tid * 16;
#pragma unroll
            for (int r = 0; r < 3; ++r)
                gl_lds16(wsrc + r * 4096, sB[buf ^ 1] + (r * 256 + tid) * 16);
            __syncthreads();
            buf ^= 1;
        }
    }

    constexpr size_t MTOT = (size_t)128 * H * W;
#pragma unroll
    for (int am = 0; am < 4; ++am)
#pragma unroll
        for (int bn = 0; bn < 2; ++bn)
#pragma unroll
            for (int rr = 0; rr < 4; ++rr) {
                int rl = wm * 64 + am * 16 + (lane >> 4) * 4 + rr;
                int col = oc0 + wn * 32 + bn * 16 + (lane & 15);
                int m = m0 + rl;
                float v = (65536.f * (float)acc[0][am][bn][rr]
                         + 256.f * (float)acc[1][am][bn][rr]
                         + (float)acc[2][am][bn][rr]) * scale;
                if (EPI == 2) {
                    outp[((size_t)kt * MTOT + m) * OC + col] = v;
                } else {
                    char sp = (v > 1.0f) ? (char)1 : (char)0;
                    if (EPI == 1) {
                        int n = m >> LHW, h = (m >> LW2) & (H - 1), w = m & (W - 1);
                        outs[((size_t)(n * (H + 2) + h + 1) * PW + (w + 1)) * OC + col] = sp;
                    } else {
                        outs[(size_t)m * OC + col] = sp;
                    }
                }
            }
}

// ---------------------------------------------- split-K combine (+spike) ----
// part: [2][128*H*H][OC] fp32 (scaled) -> i8 spikes, padded interior
template <int H, int OC>
__global__ void combine_i8_k(const float* __restrict__ part, char* __restrict__ out) {
    constexpr size_t MTOT = (size_t)128 * H * H;
    constexpr size_t TOT = MTOT * OC;
    constexpr int LH = ilog2(H);
    size_t i = ((size_t)blockIdx.x * 256 + threadIdx.x) * 4;
    if (i >= TOT) return;
    float4 a = *(const float4*)&part[i];
    float4 b = *(const float4*)&part[TOT + i];
    unsigned u = (a.x + b.x > 1.f ? 1u : 0u) | (a.y + b.y > 1.f ? 1u : 0u) << 8 |
                 (a.z + b.z > 1.f ? 1u : 0u) << 16 | (a.w + b.w > 1.f ? 1u : 0u) << 24;
    int m = (int)(i / OC), c = (int)(i % OC);
    int n = m >> (2 * LH), h = (m >> LH) & (H - 1), w = m & (H - 1);
    *(unsigned*)&out[((size_t)(n * (H + 2) + h + 1) * (H + 2) + (w + 1)) * OC + c] = u;
}

// conv7 combine fused with 2x2 avgpool -> afc1 [128][4][4][256] bf16 quarters
__global__ void comb7pool_k(const float* __restrict__ part, ushort* __restrict__ out) {
    int idx = blockIdx.x * 256 + threadIdx.x;   // 131072
    int c4 = idx & 63;
    int t = idx >> 6;
    int wo = t & 3, ho = (t >> 2) & 3, n = t >> 4;
    int c = c4 * 4;
    float4 s = {0.f, 0.f, 0.f, 0.f};
#pragma unroll
    for (int dh = 0; dh < 2; ++dh)
#pragma unroll
        for (int dw = 0; dw < 2; ++dw) {
            int m = (n * 8 + 2 * ho + dh) * 8 + 2 * wo + dw;
            float4 a = *(const float4*)&part[(size_t)m * 256 + c];
            float4 b = *(const float4*)&part[(size_t)(8192 + m) * 256 + c];
            s.x += (a.x + b.x > 1.f) ? 1.f : 0.f;
            s.y += (a.y + b.y > 1.f) ? 1.f : 0.f;
            s.z += (a.z + b.z > 1.f) ? 1.f : 0.f;
            s.w += (a.w + b.w > 1.f) ? 1.f : 0.f;
        }
    short4 o;
    o.x = (short)f2bf(s.x * 0.25f);
    o.y = (short)f2bf(s.y * 0.25f);
    o.z = (short)f2bf(s.z * 0.25f);
    o.w = (short)f2bf(s.w * 0.25f);
    *(short4*)&out[(size_t)idx * 4] = o;
}

// ------------------------------------------------------------- i8 pool ----
// in: compact NHWC i8 spikes; out: padded interior, value = 4-sum (0..4)
template <int C, int HI>
__global__ void pool_i8_k(const char* __restrict__ in, char* __restrict__ out) {
    constexpr int HO = HI / 2, C16 = C / 16;
    constexpr int TOT = 128 * HO * HO * C16;
    int idx = blockIdx.x * 256 + threadIdx.x;
    if (idx >= TOT) return;
    int c16 = idx % C16;
    int t = idx / C16;
    int w = t % HO; t /= HO;
    int h = t % HO;
    int n = t / HO;
    const char* p = in + ((size_t)(n * HI + 2 * h) * HI + 2 * w) * C + c16 * 16;
    uint4 a0 = *(const uint4*)p;
    uint4 a1 = *(const uint4*)(p + C);
    uint4 a2 = *(const uint4*)(p + (size_t)HI * C);
    uint4 a3 = *(const uint4*)(p + (size_t)HI * C + C);
    uint4 r;   // bytes are 0/1 -> packed adds never carry across byte lanes
    r.x = a0.x + a1.x + a2.x + a3.x;
    r.y = a0.y + a1.y + a2.y + a3.y;
    r.z = a0.z + a1.z + a2.z + a3.z;
    r.w = a0.w + a1.w + a2.w + a3.w;
    *(uint4*)&out[((size_t)(n * (HO + 2) + h + 1) * (HO + 2) + (w + 1)) * C + c16 * 16] = r;
}

// ----------------------------------------------------------- fc1 GEMM ----
__global__ __launch_bounds__(256) void fc1mm_k(const ushort* __restrict__ A,
                                               const ushort* __restrict__ wp,
                                               float* __restrict__ part) {
    constexpr int LW = 40;
    __shared__ ushort sA[128 * LW];
    __shared__ ushort sB[64 * LW];
    const int tid = threadIdx.x, lane = tid & 63, wid = tid >> 6;
    const int wm = wid >> 1, wn = wid & 1;
    const int j0 = blockIdx.x * 64, kt = blockIdx.y;

    int rbase[2], ldsA[2];
#pragma unroll
    for (int i = 0; i < 2; ++i) {
        int idx = i * 256 + tid;
        int r = idx >> 2, c = idx & 3;
        rbase[i] = r * 4096 + c * 8;
        ldsA[i] = r * LW + c * 8;
    }
    const int ocl = tid >> 2, cB = tid & 3;
    const int ldsBo = ocl * LW + cB * 8;

    f32x4 acc[4][2];
#pragma unroll
    for (int a = 0; a < 4; ++a) {
        acc[a][0] = (f32x4){0.f, 0.f, 0.f, 0.f};
        acc[a][1] = (f32x4){0.f, 0.f, 0.f, 0.f};
    }

    for (int st = 0; st < 12; ++st) {
        int k0 = kt * 384 + st * 32;
        int s = k0 >> 12, kk = k0 & 4095;
        __syncthreads();
#pragma unroll
        for (int i = 0; i < 2; ++i)
            *(short8v*)&sA[ldsA[i]] = *(const short8v*)&A[rbase[i] + kk];
        *(short8v*)&sB[ldsBo] =
            *(const short8v*)&wp[(((size_t)s * 128 + (kk >> 5)) * 1024 + j0 + ocl) * 32 + cB * 8];
        __syncthreads();
        short8v af[4];
#pragma unroll
        for (int am = 0; am < 4; ++am)
            af[am] = *(const short8v*)&sA[(wm * 64 + am * 16 + (lane & 15)) * LW + (lane >> 4) * 8];
        short8v b0 = *(const short8v*)&sB[(wn * 32 + (lane & 15)) * LW + (lane >> 4) * 8];
        short8v b1 = *(const short8v*)&sB[(wn * 32 + 16 + (lane & 15)) * LW + (lane >> 4) * 8];
#pragma unroll
        for (int am = 0; am < 4; ++am) {
            acc[am][0] = __builtin_amdgcn_mfma_f32_16x16x32_bf16(af[am], b0, acc[am][0], 0, 0, 0);
            acc[am][1] = __builtin_amdgcn_mfma_f32_16x16x32_bf16(af[am], b1, acc[am][1], 0, 0, 0);
        }
    }
#pragma unroll
    for (int am = 0; am < 4; ++am)
#pragma unroll
        for (int bn = 0; bn < 2; ++bn)
#pragma unroll
            for (int rr = 0; rr < 4; ++rr) {
                int row = wm * 64 + am * 16 + (lane >> 4) * 4 + rr;
                int col = j0 + wn * 32 + bn * 16 + (lane & 15);
                part[((size_t)kt * 128 + row) * 1024 + col] = acc[am][bn][rr];
            }
}

__global__ void fc1red_k(const float* __restrict__ part, float* __restrict__ mem,
                         ushort* __restrict__ sbuf) {
    int idx = blockIdx.x * 256 + threadIdx.x;   // 131072
    float y = 0.f;
#pragma unroll
    for (int kt = 0; kt < 32; ++kt) y += part[(size_t)kt * 131072 + idx];
    float m = mem[idx];
    m = 0.05f * m + 0.95f * y;
    float sp = (m > 1.f) ? 1.f : 0.f;
    m -= sp;
    mem[idx] = m;
    sbuf[idx] = sp > 0.f ? (ushort)0x3F80 : (ushort)0;
}

__global__ __launch_bounds__(256) void fc2_k(const ushort* __restrict__ S,
                                             const float* __restrict__ W2,
                                             float* __restrict__ memfc2) {
    int n = blockIdx.x, tid = threadIdx.x;
    __shared__ float red[10][256];
    const ushort* sp = S + (size_t)n * 1024 + tid * 4;
    float s0 = bf2f(sp[0]), s1 = bf2f(sp[1]), s2 = bf2f(sp[2]), s3 = bf2f(sp[3]);
#pragma unroll
    for (int o = 0; o < 10; ++o) {
        const float* w = W2 + (size_t)o * 1024 + tid * 4;
        red[o][tid] = s0 * w[0] + s1 * w[1] + s2 * w[2] + s3 * w[3];
    }
    __syncthreads();
    for (int off = 128; off >= 1; off >>= 1) {
        if (tid < off) {
#pragma unroll
            for (int o = 0; o < 10; ++o) red[o][tid] += red[o][tid + off];
        }
        __syncthreads();
    }
    if (tid < 10) memfc2[n * 10 + tid] += red[tid][0];
}

__global__ void finalize_k(const float* __restrict__ memfc2, float* __restrict__ out, int n) {
    int i = blockIdx.x * blockDim.x + threadIdx.x;
    if (i < n) out[i] = memfc2[i] * 0.1f;
}

// ---------------------------------------------------------------------------
extern "C" void kernel_launch(void* const* d_in, const int* in_sizes, int n_in,
                              void* d_out, int out_size, void* d_ws, size_t ws_size,
                              hipStream_t stream) {
    const float* inp  = (const float*)d_in[0];
    const float* w1   = (const float*)d_in[1];
    const float* w2   = (const float*)d_in[2];
    const float* w3   = (const float*)d_in[3];
    const float* w4   = (const float*)d_in[4];
    const float* w5   = (const float*)d_in[5];
    const float* w6   = (const float*)d_in[6];
    const float* w7   = (const float*)d_in[7];
    const float* fc1w = (const float*)d_in[8];
    const float* fc2w = (const float*)d_in[9];
    float* out = (float*)d_out;

    char* base = (char*)d_ws;
    size_t o = 0;
    auto alloc = [&](size_t bytes) { void* p = base + o; o += (bytes + 255) & ~(size_t)255; return p; };

    // ---- zeroed region (membranes + padded i8 spike buffers with halos) ----
    float* mem0  = (float*)alloc(33554432);      // [128][32][32][64] f32 NHWC
    float* memf1 = (float*)alloc(524288);        // [128][1024] f32
    float* memf2 = (float*)alloc(5120);          // [128][10] f32
    char*  act1  = (char*)alloc(9467904);        // [128][34][34][64] i8
    char*  act2  = (char*)alloc(2654208);        // [128][18][18][64] i8
    char*  c3out = (char*)alloc(5308416);        // [128][18][18][128] i8
    char*  act3  = (char*)alloc(1638400);        // [128][10][10][128] i8
    char*  c5out = (char*)alloc(3276800);        // [128][10][10][256] i8
    char*  c6out = (char*)alloc(3276800);        // [128][10][10][256] i8
    const size_t zero_bytes = 59706368;          // mem0 .. c6out inclusive
    // ---- non-zeroed ----
    float*  stat  = (float*)alloc(33554432);     // conv1 out, NHWC f32
    char*   bufC  = (char*)alloc(16777216);      // conv2/4 spikes | fp32 partials
    ushort* afc1  = (ushort*)alloc(1048576);     // [128][4][4][256] bf16
    ushort* sbuf  = (ushort*)alloc(262144);      // [128][1024] bf16
    char*   wq2   = (char*)alloc(110592);
    char*   wq3   = (char*)alloc(221184);
    char*   wq4   = (char*)alloc(442368);
    char*   wq5   = (char*)alloc(884736);
    char*   wq6   = (char*)alloc(1769472);
    char*   wq7   = (char*)alloc(1769472);
    ushort* wpf1  = (ushort*)alloc(25165824);
    (void)ws_size;

    {
        int n4 = (int)(zero_bytes / 16);
        zero4_k<<<(n4 + 255) / 256, 256, 0, stream>>>((float4*)mem0, n4);
    }
    prep_convw_i8_k<64, 64>  <<<(36864 + 255) / 256, 256, 0, stream>>>(w2, wq2);
    prep_convw_i8_k<64, 128> <<<(73728 + 255) / 256, 256, 0, stream>>>(w3, wq3);
    prep_convw_i8_k<128, 128><<<(147456 + 255) / 256, 256, 0, stream>>>(w4, wq4);
    prep_convw_i8_k<128, 256><<<(294912 + 255) / 256, 256, 0, stream>>>(w5, wq5);
    prep_convw_i8_k<256, 256><<<(589824 + 255) / 256, 256, 0, stream>>>(w6, wq6);
    prep_convw_i8_k<256, 256><<<(589824 + 255) / 256, 256, 0, stream>>>(w7, wq7);
    prep_fc1w_k<<<(4194304 + 255) / 256, 256, 0, stream>>>(fc1w, wpf1);

    conv1_k<<<2048, 256, 0, stream>>>(inp, w1, stat);

    for (int t = 0; t < 10; ++t) {
        lif0_k<<<8192, 256, 0, stream>>>(stat, mem0, act1);

        convi8_k<32, 32, 64, 64, 1, 4, 1, 0>
            <<<dim3(1024, 1, 1), 256, 0, stream>>>(act1, wq2, bufC, nullptr, SC21);
        pool_i8_k<64, 32><<<512, 256, 0, stream>>>(bufC, act2);

        convi8_k<16, 16, 64, 128, 1, 8, 1, 1>
            <<<dim3(256, 2, 1), 256, 0, stream>>>(act2, wq3, c3out, nullptr, SC23);
        convi8_k<16, 16, 128, 128, 1, 8, 1, 0>
            <<<dim3(256, 2, 1), 256, 0, stream>>>(c3out, wq4, bufC, nullptr, SC21);
        pool_i8_k<128, 16><<<256, 256, 0, stream>>>(bufC, act3);

        convi8_k<8, 8, 128, 256, 2, 8, 2, 2>
            <<<dim3(64, 4, 2), 256, 0, stream>>>(act3, wq5, nullptr, (float*)bufC, SC23);
        combine_i8_k<8, 256><<<2048, 256, 0, stream>>>((const float*)bufC, c5out);
        convi8_k<8, 8, 256, 256, 2, 8, 2, 2>
            <<<dim3(64, 4, 2), 256, 0, stream>>>(c5out, wq6, nullptr, (float*)bufC, SC21);
        combine_i8_k<8, 256><<<2048, 256, 0, stream>>>((const float*)bufC, c6out);
        convi8_k<8, 8, 256, 256, 2, 8, 2, 2>
            <<<dim3(64, 4, 2), 256, 0, stream>>>(c6out, wq7, nullptr, (float*)bufC, SC21);
        comb7pool_k<<<512, 256, 0, stream>>>((const float*)bufC, afc1);

        fc1mm_k<<<dim3(16, 32), 256, 0, stream>>>(afc1, wpf1, (float*)bufC);
        fc1red_k<<<512, 256, 0, stream>>>((const float*)bufC, memf1, sbuf);
        fc2_k<<<128, 256, 0, stream>>>(sbuf, fc2w, memf2);
    }

    finalize_k<<<(1280 + 255) / 256, 256, 0, stream>>>(memf2, out, 1280);
}

// Round 6
// 899.284 us; speedup vs baseline: 2.3018x; 1.7742x over previous
//
#include <hip/hip_runtime.h>

// ---------------------------------------------------------------------------
// Spiking VGG9, 10 steps, B=128.  R6: time-unrolled batch-1280 pipeline.
//  - conv1+LIF fused: 10-step per-element recurrence in registers -> 10 spike
//    planes written once (batch index n' = t*128 + n)
//  - conv2..7, pools, fc1-GEMM batched over 1280 images, ONE dispatch each
//    (no split-K, no combine kernels; spike epilogue everywhere)
//  - i8 path: acts {0,1} / {0..4}; weights = 3 balanced i8 digits on 2^-21
//    grid; mfma_i32_16x16x64_i8; i32 accum exact; double digit-fold epilogue
//  - only fc1-LIF recurrence + fc2 accumulation stay sequential in t (exact
//    reference order)
// ---------------------------------------------------------------------------

typedef __attribute__((ext_vector_type(4))) int int32x4;

__device__ __forceinline__ float bf2f(ushort h) {
    union { unsigned u; float f; } v; v.u = ((unsigned)h) << 16;
    return v.f;
}
constexpr int ilog2(int x) { int r = 0; while (x > 1) { x >>= 1; ++r; } return r; }

__device__ __forceinline__ void gl_lds16(const void* g, void* l) {
    __builtin_amdgcn_global_load_lds(
        (const __attribute__((address_space(1))) unsigned int*)g,
        (__attribute__((address_space(3))) unsigned int*)l, 16, 0, 0);
}

#define SC21 4.76837158203125e-07    // 2^-21  (acts are spikes {0,1})
#define SC23 1.1920928955078125e-07  // 2^-23  (acts are ints 0..4 = 4*act)

// ------------------------------------------------------------ weight prep --
// OIHW fp32 -> 3 balanced i8 digits, layout [slab][q][oct][c(4)][R(192)][16],
// R = s*64 + ocl, chunk c covers ic (kin) c*16..c*16+15.
template <int IC, int OC>
__global__ void prep_convw_i8_k(const float* __restrict__ w, char* __restrict__ dst) {
    int idx = blockIdx.x * 256 + threadIdx.x;
    if (idx >= OC * IC * 9) return;
    int oc = idx / (IC * 9);
    int rem = idx % (IC * 9);
    int ic = rem / 9, q = rem % 9;
    int wq_ = (int)rintf(w[idx] * 2097152.0f);   // 2^21 grid
    int a2 = ((wq_ + 128) & 255) - 128;
    int t2 = (wq_ - a2) >> 8;
    int a1 = ((t2 + 128) & 255) - 128;
    int a0 = (t2 - a1) >> 8;
    int sg = ic >> 6, kin = ic & 63, c = kin >> 4, bb = kin & 15;
    int oct = oc >> 6, ocl = oc & 63;
    constexpr int OCT = OC / 64;
    size_t base = ((size_t)(sg * 9 + q) * OCT + oct) * 12288;
    char digs[3] = {(char)a0, (char)a1, (char)a2};
#pragma unroll
    for (int s = 0; s < 3; ++s)
        dst[base + (size_t)(c * 192 + s * 64 + ocl) * 16 + bb] = digs[s];
}

// fc1 [1024][4096] fp32; col k=(c*16+hw) -> k'=hw*256+c (matches pooled NHWC
// flatten). 3 digits, layout [slab(64)][oct(16)][c(4)][R(192)][16].
__global__ void prep_fc1w_i8_k(const float* __restrict__ w, char* __restrict__ dst) {
    int idx = blockIdx.x * 256 + threadIdx.x;
    if (idx >= 1024 * 4096) return;
    int j = idx >> 12, k = idx & 4095;
    int c = k >> 4, hw = k & 15;
    int kp = hw * 256 + c;
    int wq_ = (int)rintf(w[idx] * 2097152.0f);
    int a2 = ((wq_ + 128) & 255) - 128;
    int t2 = (wq_ - a2) >> 8;
    int a1 = ((t2 + 128) & 255) - 128;
    int a0 = (t2 - a1) >> 8;
    int slab = kp >> 6, kin = kp & 63, cch = kin >> 4, bb = kin & 15;
    int oct = j >> 6, ocl = j & 63;
    size_t base = ((size_t)(slab * 16 + oct)) * 12288;
    char digs[3] = {(char)a0, (char)a1, (char)a2};
#pragma unroll
    for (int s = 0; s < 3; ++s)
        dst[base + (size_t)(cch * 192 + s * 64 + ocl) * 16 + bb] = digs[s];
}

// ------------------------------------------------------------- halo zero ----
// zeros the 1-px spatial halo of [1280][H+2][H+2][C] i8
template <int H, int C>
__global__ void halo0_k(char* __restrict__ buf) {
    constexpr int P = 4 * H + 4;
    constexpr int CPI = P * (C / 16);
    int idx = blockIdx.x * 256 + threadIdx.x;
    if (idx >= 1280 * CPI) return;
    int n = idx / CPI, r = idx % CPI;
    int p = r / (C / 16), c16 = r % (C / 16);
    int row, col;
    if (p < 2 * (H + 2)) { row = (p < H + 2) ? 0 : H + 1; col = p % (H + 2); }
    else { int qq = p - 2 * (H + 2); col = (qq < H) ? 0 : H + 1; row = 1 + (qq % H); }
    *(uint4*)&buf[(((size_t)n * (H + 2) + row) * (H + 2) + col) * C + c16 * 16] =
        (uint4){0u, 0u, 0u, 0u};
}

// ------------------------------------------------- conv1 + 10-step LIF ------
// writes 10 spike planes into act1 [1280][34][34][64] i8 (n' = t*128+n)
__global__ __launch_bounds__(256) void conv1lif_k(const float* __restrict__ inp,
                                                  const float* __restrict__ w1,
                                                  char* __restrict__ act1) {
    __shared__ float ws[27 * 64];
    for (int e = threadIdx.x; e < 1728; e += 256) {
        int oc = e / 27, j = e % 27;
        ws[j * 64 + oc] = w1[e];
    }
    __syncthreads();
    int t = blockIdx.x * 256 + threadIdx.x;   // 524288 = 131072 px * 4
    int q = t & 3;
    int m = t >> 2;
    int n = m >> 10, h = (m >> 5) & 31, w = m & 31;
    float xv[27];
#pragma unroll
    for (int ic = 0; ic < 3; ++ic)
#pragma unroll
        for (int kh = 0; kh < 3; ++kh)
#pragma unroll
            for (int kw = 0; kw < 3; ++kw) {
                int r = h + kh - 1, c = w + kw - 1;
                xv[ic * 9 + kh * 3 + kw] =
                    (r >= 0 && r < 32 && c >= 0 && c < 32)
                        ? inp[(n * 3 + ic) * 1024 + r * 32 + c] : 0.0f;
            }
    float s[16], mem[16];
#pragma unroll
    for (int o = 0; o < 16; ++o) { s[o] = 0.f; mem[o] = 0.f; }
#pragma unroll
    for (int j = 0; j < 27; ++j) {
        float x = xv[j];
        const float* wr = &ws[j * 64 + q * 16];
#pragma unroll
        for (int o = 0; o < 16; ++o) s[o] += wr[o] * x;
    }
    const size_t dbase = (((size_t)h + 1) * 34 + (w + 1)) * 64 + q * 16;
    for (int st = 0; st < 10; ++st) {
        unsigned r[4];
#pragma unroll
        for (int g = 0; g < 4; ++g) {
            unsigned acc = 0;
#pragma unroll
            for (int e = 0; e < 4; ++e) {
                int o = g * 4 + e;
                mem[o] = 0.05f * mem[o] + 0.95f * s[o];
                unsigned b = (mem[o] > 1.f) ? 1u : 0u;
                mem[o] -= (float)b;
                acc |= b << (8 * e);
            }
            r[g] = acc;
        }
        size_t d = ((size_t)(st * 128 + n) * 34 * 34) * 64 + dbase;
        *(uint4*)&act1[d] = (uint4){r[0], r[1], r[2], r[3]};
    }
}

// --------------------------------------------------- i8 implicit-GEMM conv --
// act: padded NHWC i8 [n'][H+2][W+2][IC]; wq per prep_convw_i8_k.
// Block: 128 px x 64 oc, 4 waves (2x2).  EPI: 0 = spike compact, 1 = padded.
template <int H, int W, int IC, int OC, int NI, int MR, int EPI>
__global__ __launch_bounds__(256) void convi8_k(const char* __restrict__ act,
                                                const char* __restrict__ wq,
                                                char* __restrict__ outs,
                                                float scale) {
    constexpr int PW = W + 2, PHR = MR + 2;
    constexpr int MBLK = NI * MR * W;
    constexpr int NPIX = NI * PHR * PW;
    constexpr int ACH = NPIX * 4;
    constexpr int HR = (ACH + 255) / 256;
    constexpr int SLABS = IC / 64;
    constexpr int OCT = OC / 64;
    constexpr int LHW = ilog2(H * W), LW2 = ilog2(W), LMW = ilog2(MR * W);
    static_assert(MBLK == 128, "tile mapping");

    __shared__ __align__(16) char sA[NPIX * 64];
    __shared__ __align__(16) char sB[2][12288];

    const int tid = threadIdx.x, lane = tid & 63;
    const int wid = tid >> 6, wm = wid >> 1, wn = wid & 1;
    const int b = blockIdx.x, oct = blockIdx.y;
    const int oc0 = oct * 64;
    const int m0 = b * MBLK;
    constexpr int TPI = (NI == 1) ? (H / MR) : 1;
    const int n0 = (NI == 1) ? (b / TPI) : (b * NI);
    const int h0 = (NI == 1) ? (b % TPI) * MR : 0;

    int asrc[HR]; bool apred[HR];
#pragma unroll
    for (int r = 0; r < HR; ++r) {
        int i = r * 256 + tid;
        apred[r] = (i < ACH);
        int ii = apred[r] ? i : 0;
        int c = ii / NPIX, pix = ii % NPIX;
        int pc = pix % PW, t2 = pix / PW;
        int hp = t2 % PHR, img = t2 / PHR;
        asrc[r] = (((n0 + img) * (H + 2) + h0 + hp) * PW + pc) * IC + c * 16;
    }
    int apix[4];
#pragma unroll
    for (int am = 0; am < 4; ++am) {
        int p = wm * 64 + am * 16 + (lane & 15);
        int img = p >> LMW;
        int pi = p & ((MR * W) - 1);
        int h = pi >> LW2;
        apix[am] = (img * PHR + h) * PW + (pi & (W - 1));
    }
    const int cA = lane >> 4;

    int32x4 acc[3][4][2];
#pragma unroll
    for (int s = 0; s < 3; ++s)
#pragma unroll
        for (int a = 0; a < 4; ++a)
#pragma unroll
            for (int bn = 0; bn < 2; ++bn) acc[s][a][bn] = (int32x4){0, 0, 0, 0};

    const size_t wqoct = (size_t)oct * 12288;
    int buf = 0;
    {   // prologue: halo(slab0) + B(slab0, q=0)
#pragma unroll
        for (int r = 0; r < HR; ++r)
            if (apred[r]) gl_lds16(act + asrc[r], sA + (r * 256 + tid) * 16);
        const char* wsrc = wq + wqoct + tid * 16;
#pragma unroll
        for (int r = 0; r < 3; ++r)
            gl_lds16(wsrc + r * 4096, sB[0] + (r * 256 + tid) * 16);
    }
    __syncthreads();

    for (int sl = 0; sl < SLABS; ++sl) {
        for (int q = 0; q < 9; ++q) {
            if (q < 8) {
                const char* wsrc = wq + (size_t)(sl * 9 + q + 1) * OCT * 12288 + wqoct + tid * 16;
#pragma unroll
                for (int r = 0; r < 3; ++r)
                    gl_lds16(wsrc + r * 4096, sB[buf ^ 1] + (r * 256 + tid) * 16);
            }
            const int qr = q / 3, qc = q % 3;
            int32x4 af[4];
#pragma unroll
            for (int am = 0; am < 4; ++am) {
                int pix = apix[am] + qr * PW + qc;
                af[am] = *(const int32x4*)&sA[(cA * NPIX + pix) * 16];
            }
#pragma unroll
            for (int s = 0; s < 3; ++s)
#pragma unroll
                for (int bn = 0; bn < 2; ++bn) {
                    int R = s * 64 + wn * 32 + bn * 16 + (lane & 15);
                    int32x4 bf = *(const int32x4*)&sB[buf][(cA * 192 + R) * 16];
#pragma unroll
                    for (int am = 0; am < 4; ++am)
                        acc[s][am][bn] = __builtin_amdgcn_mfma_i32_16x16x64_i8(
                            af[am], bf, acc[s][am][bn], 0, 0, 0);
                }
            if (q < 8) {
                __syncthreads();
                buf ^= 1;
            }
        }
        if (sl + 1 < SLABS) {
            const int sg2 = sl + 1;
            __syncthreads();
#pragma unroll
            for (int r = 0; r < HR; ++r)
                if (apred[r]) gl_lds16(act + asrc[r] + sg2 * 64, sA + (r * 256 + tid) * 16);
            const char* wsrc = wq + (size_t)(sg2 * 9) * OCT * 12288 + wqoct + tid * 16;
#pragma unroll
            for (int r = 0; r < 3; ++r)
                gl_lds16(wsrc + r * 4096, sB[buf ^ 1] + (r * 256 + tid) * 16);
            __syncthreads();
            buf ^= 1;
        }
    }

    const double dscale = (double)scale;
#pragma unroll
    for (int am = 0; am < 4; ++am)
#pragma unroll
        for (int bn = 0; bn < 2; ++bn)
#pragma unroll
            for (int rr = 0; rr < 4; ++rr) {
                int rl = wm * 64 + am * 16 + (lane >> 4) * 4 + rr;
                int col = oc0 + wn * 32 + bn * 16 + (lane & 15);
                int m = m0 + rl;
                float v = (float)((65536.0 * (double)acc[0][am][bn][rr]
                                 + 256.0 * (double)acc[1][am][bn][rr]
                                 + (double)acc[2][am][bn][rr]) * dscale);
                char sp = (v > 1.0f) ? (char)1 : (char)0;
                if (EPI == 1) {
                    int n = m >> LHW, h = (m >> LW2) & (H - 1), w = m & (W - 1);
                    outs[((size_t)(n * (H + 2) + h + 1) * PW + (w + 1)) * OC + col] = sp;
                } else {
                    outs[(size_t)m * OC + col] = sp;
                }
            }
}

// ------------------------------------------------------------- i8 pool ----
// in: compact [1280][HI][HI][C] i8 spikes; out: padded interior, 4-sum 0..4
template <int C, int HI>
__global__ void pool_i8_k(const char* __restrict__ in, char* __restrict__ out) {
    constexpr int HO = HI / 2, C16 = C / 16;
    constexpr int TOT = 1280 * HO * HO * C16;
    int idx = blockIdx.x * 256 + threadIdx.x;
    if (idx >= TOT) return;
    int c16 = idx % C16;
    int t = idx / C16;
    int w = t % HO; t /= HO;
    int h = t % HO;
    int n = t / HO;
    const char* p = in + ((size_t)(n * HI + 2 * h) * HI + 2 * w) * C + c16 * 16;
    uint4 a0 = *(const uint4*)p;
    uint4 a1 = *(const uint4*)(p + C);
    uint4 a2 = *(const uint4*)(p + (size_t)HI * C);
    uint4 a3 = *(const uint4*)(p + (size_t)HI * C + C);
    uint4 r;   // bytes 0/1 -> no cross-byte carries
    r.x = a0.x + a1.x + a2.x + a3.x;
    r.y = a0.y + a1.y + a2.y + a3.y;
    r.z = a0.z + a1.z + a2.z + a3.z;
    r.w = a0.w + a1.w + a2.w + a3.w;
    *(uint4*)&out[((size_t)(n * (HO + 2) + h + 1) * (HO + 2) + (w + 1)) * C + c16 * 16] = r;
}

// pool3: c7out compact [1280][8][8][256] spikes -> afc1 [1280][4096] i8 (0..4)
__global__ void pool3q_k(const char* __restrict__ in, char* __restrict__ out) {
    int idx = blockIdx.x * 256 + threadIdx.x;   // 1280*16*16 = 327680
    if (idx >= 327680) return;
    int c16 = idx & 15;
    int t = idx >> 4;
    int wo = t & 3, ho = (t >> 2) & 3, n = t >> 4;
    const char* p = in + ((size_t)(n * 8 + 2 * ho) * 8 + 2 * wo) * 256 + c16 * 16;
    uint4 a0 = *(const uint4*)p;
    uint4 a1 = *(const uint4*)(p + 256);
    uint4 a2 = *(const uint4*)(p + 2048);
    uint4 a3 = *(const uint4*)(p + 2048 + 256);
    uint4 r;
    r.x = a0.x + a1.x + a2.x + a3.x;
    r.y = a0.y + a1.y + a2.y + a3.y;
    r.z = a0.z + a1.z + a2.z + a3.z;
    r.w = a0.w + a1.w + a2.w + a3.w;
    *(uint4*)&out[((size_t)(n * 16 + ho * 4 + wo) * 16 + c16) * 16] = r;
}

// ----------------------------------------------------------- fc1 i8 GEMM ----
// A [1280][4096] i8, wq [slab64][oct16][12288], part [2][1280][1024] f32
__global__ __launch_bounds__(256) void fc1i8_k(const char* __restrict__ A,
                                               const char* __restrict__ wq,
                                               float* __restrict__ part) {
    __shared__ __align__(16) char sA[2][8192];
    __shared__ __align__(16) char sB[2][12288];
    const int tid = threadIdx.x, lane = tid & 63;
    const int wid = tid >> 6, wm = wid >> 1, wn = wid & 1;
    const int m0 = blockIdx.x * 128, oct = blockIdx.y, kt = blockIdx.z;

    int32x4 acc[3][4][2];
#pragma unroll
    for (int s = 0; s < 3; ++s)
#pragma unroll
        for (int a = 0; a < 4; ++a)
#pragma unroll
            for (int bn = 0; bn < 2; ++bn) acc[s][a][bn] = (int32x4){0, 0, 0, 0};

    auto stageA = [&](int sg, int bf_) {
#pragma unroll
        for (int r = 0; r < 2; ++r) {
            int i = r * 256 + tid;
            int c = i >> 7, pix = i & 127;
            gl_lds16(A + (size_t)(m0 + pix) * 4096 + sg * 64 + c * 16,
                     sA[bf_] + (size_t)i * 16);
        }
    };
    auto stageB = [&](int sg, int bf_) {
        const char* src = wq + ((size_t)(sg * 16 + oct)) * 12288 + tid * 16;
#pragma unroll
        for (int r = 0; r < 3; ++r)
            gl_lds16(src + r * 4096, sB[bf_] + (r * 256 + tid) * 16);
    };

    int buf = 0;
    stageA(kt * 32, 0);
    stageB(kt * 32, 0);
    __syncthreads();
    const int cA = lane >> 4;
    for (int sl = 0; sl < 32; ++sl) {
        int sg = kt * 32 + sl;
        if (sl < 31) { stageA(sg + 1, buf ^ 1); stageB(sg + 1, buf ^ 1); }
        int32x4 af[4];
#pragma unroll
        for (int am = 0; am < 4; ++am)
            af[am] = *(const int32x4*)&sA[buf][(cA * 128 + wm * 64 + am * 16 + (lane & 15)) * 16];
#pragma unroll
        for (int s = 0; s < 3; ++s)
#pragma unroll
            for (int bn = 0; bn < 2; ++bn) {
                int R = s * 64 + wn * 32 + bn * 16 + (lane & 15);
                int32x4 bf = *(const int32x4*)&sB[buf][(cA * 192 + R) * 16];
#pragma unroll
                for (int am = 0; am < 4; ++am)
                    acc[s][am][bn] = __builtin_amdgcn_mfma_i32_16x16x64_i8(
                        af[am], bf, acc[s][am][bn], 0, 0, 0);
            }
        if (sl < 31) { __syncthreads(); buf ^= 1; }
    }
#pragma unroll
    for (int am = 0; am < 4; ++am)
#pragma unroll
        for (int bn = 0; bn < 2; ++bn)
#pragma unroll
            for (int rr = 0; rr < 4; ++rr) {
                int row = m0 + wm * 64 + am * 16 + (lane >> 4) * 4 + rr;
                int col = oct * 64 + wn * 32 + bn * 16 + (lane & 15);
                float v = (float)((65536.0 * (double)acc[0][am][bn][rr]
                                 + 256.0 * (double)acc[1][am][bn][rr]
                                 + (double)acc[2][am][bn][rr]) * SC23);
                part[((size_t)kt * 1280 + row) * 1024 + col] = v;
            }
}

// fc1 LIF recurrence over t (exact reference order), spikes -> sbuf bf16
__global__ void fc1lif_k(const float* __restrict__ part, ushort* __restrict__ sbuf) {
    int idx = blockIdx.x * 256 + threadIdx.x;   // 131072: n = idx>>10, j low
    int n = idx >> 10, j = idx & 1023;
    float m = 0.f;
    for (int t = 0; t < 10; ++t) {
        size_t row = (size_t)(t * 128 + n) * 1024 + j;
        float y = part[row] + part[1310720 + row];
        m = 0.05f * m + 0.95f * y;
        float sp = (m > 1.f) ? 1.f : 0.f;
        m -= sp;
        sbuf[row] = sp > 0.f ? (ushort)0x3F80 : (ushort)0;
    }
}

// fc2: mem_fc2[n][o] = sum_t S_t[n] . W2[o]  (per-t tree, t in order), /10
__global__ __launch_bounds__(256) void fc2o_k(const ushort* __restrict__ S,
                                              const float* __restrict__ W2,
                                              float* __restrict__ out) {
    __shared__ float wsh[10 * 1024];
    __shared__ float red[10][256];
    int n = blockIdx.x, tid = threadIdx.x;
    for (int e = tid; e < 10240; e += 256) wsh[e] = W2[e];
    __syncthreads();
    float accv = 0.f;
    for (int t = 0; t < 10; ++t) {
        const ushort* sp = S + ((size_t)(t * 128 + n)) * 1024 + tid * 4;
        float s0 = bf2f(sp[0]), s1 = bf2f(sp[1]), s2 = bf2f(sp[2]), s3 = bf2f(sp[3]);
#pragma unroll
        for (int o = 0; o < 10; ++o) {
            const float* w = &wsh[o * 1024 + tid * 4];
            red[o][tid] = s0 * w[0] + s1 * w[1] + s2 * w[2] + s3 * w[3];
        }
        __syncthreads();
        for (int off = 128; off >= 1; off >>= 1) {
            if (tid < off) {
#pragma unroll
                for (int o = 0; o < 10; ++o) red[o][tid] += red[o][tid + off];
            }
            __syncthreads();
        }
        if (tid < 10) accv += red[tid][0];
        __syncthreads();
    }
    if (tid < 10) out[n * 10 + tid] = accv * 0.1f;
}

// ---------------------------------------------------------------------------
extern "C" void kernel_launch(void* const* d_in, const int* in_sizes, int n_in,
                              void* d_out, int out_size, void* d_ws, size_t ws_size,
                              hipStream_t stream) {
    const float* inp  = (const float*)d_in[0];
    const float* w1   = (const float*)d_in[1];
    const float* w2   = (const float*)d_in[2];
    const float* w3   = (const float*)d_in[3];
    const float* w4   = (const float*)d_in[4];
    const float* w5   = (const float*)d_in[5];
    const float* w6   = (const float*)d_in[6];
    const float* w7   = (const float*)d_in[7];
    const float* fc1w = (const float*)d_in[8];
    const float* fc2w = (const float*)d_in[9];
    float* out = (float*)d_out;

    char* base = (char*)d_ws;
    // Two big aliased arenas + persistent small buffers.
    char* arenaA = base;                          // 94,679,040 B
    char* arenaB = base + 94679040;               // 83,886,080 B
    size_t o = 94679040 + 83886080;
    auto alloc = [&](size_t bytes) { void* p = base + o; o += (bytes + 255) & ~(size_t)255; return p; };
    char*   wq2  = (char*)alloc(110592);
    char*   wq3  = (char*)alloc(221184);
    char*   wq4  = (char*)alloc(442368);
    char*   wq5  = (char*)alloc(884736);
    char*   wq6  = (char*)alloc(1769472);
    char*   wq7  = (char*)alloc(1769472);
    char*   wqf1 = (char*)alloc(12582912);
    ushort* sbuf = (ushort*)alloc(2621440);       // [1280][1024] bf16
    (void)ws_size;

    // arena A/B phase pointers
    char*  act1  = arenaA;                        // [1280][34][34][64]
    char*  c2out = arenaB;                        // [1280][32][32][64]
    char*  act2  = arenaA;                        // [1280][18][18][64]
    char*  c3out = arenaB;                        // [1280][18][18][128]
    char*  c4out = arenaA;                        // [1280][16][16][128]
    char*  act3  = arenaA + 41943040;             // [1280][10][10][128]
    char*  c5out = arenaB;                        // [1280][10][10][256]
    char*  c6out = arenaB + 33554432;             // [1280][10][10][256]
    char*  c7out = arenaA;                        // [1280][8][8][256]
    char*  afc1  = arenaA + 20971520;             // [1280][4096] i8
    float* part  = (float*)(arenaA + 26214400);   // [2][1280][1024] f32

    // weight prep
    prep_convw_i8_k<64, 64>  <<<(36864 + 255) / 256, 256, 0, stream>>>(w2, wq2);
    prep_convw_i8_k<64, 128> <<<(73728 + 255) / 256, 256, 0, stream>>>(w3, wq3);
    prep_convw_i8_k<128, 128><<<(147456 + 255) / 256, 256, 0, stream>>>(w4, wq4);
    prep_convw_i8_k<128, 256><<<(294912 + 255) / 256, 256, 0, stream>>>(w5, wq5);
    prep_convw_i8_k<256, 256><<<(589824 + 255) / 256, 256, 0, stream>>>(w6, wq6);
    prep_convw_i8_k<256, 256><<<(589824 + 255) / 256, 256, 0, stream>>>(w7, wq7);
    prep_fc1w_i8_k<<<(4194304 + 255) / 256, 256, 0, stream>>>(fc1w, wqf1);

    // layer 1: conv1 + 10-step LIF -> act1 (halos zeroed first)
    halo0_k<32, 64><<<(1280 * 132 * 4 + 255) / 256, 256, 0, stream>>>(act1);
    conv1lif_k<<<2048, 256, 0, stream>>>(inp, w1, act1);

    // conv2 (batch 1280): act1 -> c2out compact
    convi8_k<32, 32, 64, 64, 1, 4, 0>
        <<<dim3(10240, 1), 256, 0, stream>>>(act1, wq2, c2out, (float)SC21);
    // pool1 -> act2 padded   (act1 dead; zero act2 halos in arena A)
    halo0_k<16, 64><<<(1280 * 68 * 4 + 255) / 256, 256, 0, stream>>>(act2);
    pool_i8_k<64, 32><<<(1280 * 256 * 4 + 255) / 256, 256, 0, stream>>>(c2out, act2);

    // conv3: act2 -> c3out padded  (c2out dead; c3out in arena B)
    halo0_k<16, 128><<<(1280 * 68 * 8 + 255) / 256, 256, 0, stream>>>(c3out);
    convi8_k<16, 16, 64, 128, 1, 8, 1>
        <<<dim3(2560, 2), 256, 0, stream>>>(act2, wq3, c3out, (float)SC23);
    // conv4: c3out -> c4out compact (act2 dead; c4out at arena A base)
    convi8_k<16, 16, 128, 128, 1, 8, 0>
        <<<dim3(2560, 2), 256, 0, stream>>>(c3out, wq4, c4out, (float)SC21);
    // pool2 -> act3 padded (A + 41.9MB)
    halo0_k<8, 128><<<(1280 * 36 * 8 + 255) / 256, 256, 0, stream>>>(act3);
    pool_i8_k<128, 16><<<(1280 * 64 * 8 + 255) / 256, 256, 0, stream>>>(c4out, act3);

    // conv5: act3 -> c5out padded (c3out dead; c5out at arena B base)
    halo0_k<8, 256><<<(1280 * 36 * 16 + 255) / 256, 256, 0, stream>>>(c5out);
    convi8_k<8, 8, 128, 256, 2, 8, 1>
        <<<dim3(640, 4), 256, 0, stream>>>(act3, wq5, c5out, (float)SC23);
    // conv6: c5out -> c6out padded (B + 33.55MB)
    halo0_k<8, 256><<<(1280 * 36 * 16 + 255) / 256, 256, 0, stream>>>(c6out);
    convi8_k<8, 8, 256, 256, 2, 8, 1>
        <<<dim3(640, 4), 256, 0, stream>>>(c5out, wq6, c6out, (float)SC21);
    // conv7: c6out -> c7out compact (arena A base; c4out/act3 dead)
    convi8_k<8, 8, 256, 256, 2, 8, 0>
        <<<dim3(640, 4), 256, 0, stream>>>(c6out, wq7, c7out, (float)SC21);

    // pool3 + quantize -> afc1 ints 0..4
    pool3q_k<<<(327680 + 255) / 256, 256, 0, stream>>>(c7out, afc1);

    // fc1 GEMM (M=1280, split-K 2) -> part
    fc1i8_k<<<dim3(10, 16, 2), 256, 0, stream>>>(afc1, wqf1, part);
    // fc1 LIF recurrence (exact order) -> sbuf
    fc1lif_k<<<512, 256, 0, stream>>>(part, sbuf);
    // fc2 accumulate over t (exact order) -> out/10
    fc2o_k<<<128, 256, 0, stream>>>(sbuf, fc2w, out);
}

// Round 7
// 887.440 us; speedup vs baseline: 2.3326x; 1.0133x over previous
//
#include <hip/hip_runtime.h>

// ---------------------------------------------------------------------------
// Spiking VGG9, 10 steps, B=128.  R7: counted-vmcnt pipelined conv.
//  - convi8_k tap loop: 3-buffer B rotation, ONE s_barrier per unit,
//    s_waitcnt vmcnt(3) (never 0 mid-slab) -> B(u+2) staged 2 units ahead
//    and hidden under MFMA; s_setprio(1) around the MFMA cluster
//  - everything else identical to R6 (time-unrolled batch-1280, i8 3-digit
//    exact weights, mfma_i32_16x16x64_i8, fc1/fc2 sequential-in-t)
// ---------------------------------------------------------------------------

typedef __attribute__((ext_vector_type(4))) int int32x4;

__device__ __forceinline__ float bf2f(ushort h) {
    union { unsigned u; float f; } v; v.u = ((unsigned)h) << 16;
    return v.f;
}
constexpr int ilog2(int x) { int r = 0; while (x > 1) { x >>= 1; ++r; } return r; }

__device__ __forceinline__ void gl_lds16(const void* g, void* l) {
    __builtin_amdgcn_global_load_lds(
        (const __attribute__((address_space(1))) unsigned int*)g,
        (__attribute__((address_space(3))) unsigned int*)l, 16, 0, 0);
}

#define SC21 4.76837158203125e-07    // 2^-21  (acts are spikes {0,1})
#define SC23 1.1920928955078125e-07  // 2^-23  (acts are ints 0..4 = 4*act)

// ------------------------------------------------------------ weight prep --
template <int IC, int OC>
__global__ void prep_convw_i8_k(const float* __restrict__ w, char* __restrict__ dst) {
    int idx = blockIdx.x * 256 + threadIdx.x;
    if (idx >= OC * IC * 9) return;
    int oc = idx / (IC * 9);
    int rem = idx % (IC * 9);
    int ic = rem / 9, q = rem % 9;
    int wq_ = (int)rintf(w[idx] * 2097152.0f);   // 2^21 grid
    int a2 = ((wq_ + 128) & 255) - 128;
    int t2 = (wq_ - a2) >> 8;
    int a1 = ((t2 + 128) & 255) - 128;
    int a0 = (t2 - a1) >> 8;
    int sg = ic >> 6, kin = ic & 63, c = kin >> 4, bb = kin & 15;
    int oct = oc >> 6, ocl = oc & 63;
    constexpr int OCT = OC / 64;
    size_t base = ((size_t)(sg * 9 + q) * OCT + oct) * 12288;
    char digs[3] = {(char)a0, (char)a1, (char)a2};
#pragma unroll
    for (int s = 0; s < 3; ++s)
        dst[base + (size_t)(c * 192 + s * 64 + ocl) * 16 + bb] = digs[s];
}

__global__ void prep_fc1w_i8_k(const float* __restrict__ w, char* __restrict__ dst) {
    int idx = blockIdx.x * 256 + threadIdx.x;
    if (idx >= 1024 * 4096) return;
    int j = idx >> 12, k = idx & 4095;
    int c = k >> 4, hw = k & 15;
    int kp = hw * 256 + c;
    int wq_ = (int)rintf(w[idx] * 2097152.0f);
    int a2 = ((wq_ + 128) & 255) - 128;
    int t2 = (wq_ - a2) >> 8;
    int a1 = ((t2 + 128) & 255) - 128;
    int a0 = (t2 - a1) >> 8;
    int slab = kp >> 6, kin = kp & 63, cch = kin >> 4, bb = kin & 15;
    int oct = j >> 6, ocl = j & 63;
    size_t base = ((size_t)(slab * 16 + oct)) * 12288;
    char digs[3] = {(char)a0, (char)a1, (char)a2};
#pragma unroll
    for (int s = 0; s < 3; ++s)
        dst[base + (size_t)(cch * 192 + s * 64 + ocl) * 16 + bb] = digs[s];
}

// ------------------------------------------------------------- halo zero ----
template <int H, int C>
__global__ void halo0_k(char* __restrict__ buf) {
    constexpr int P = 4 * H + 4;
    constexpr int CPI = P * (C / 16);
    int idx = blockIdx.x * 256 + threadIdx.x;
    if (idx >= 1280 * CPI) return;
    int n = idx / CPI, r = idx % CPI;
    int p = r / (C / 16), c16 = r % (C / 16);
    int row, col;
    if (p < 2 * (H + 2)) { row = (p < H + 2) ? 0 : H + 1; col = p % (H + 2); }
    else { int qq = p - 2 * (H + 2); col = (qq < H) ? 0 : H + 1; row = 1 + (qq % H); }
    *(uint4*)&buf[(((size_t)n * (H + 2) + row) * (H + 2) + col) * C + c16 * 16] =
        (uint4){0u, 0u, 0u, 0u};
}

// ------------------------------------------------- conv1 + 10-step LIF ------
__global__ __launch_bounds__(256) void conv1lif_k(const float* __restrict__ inp,
                                                  const float* __restrict__ w1,
                                                  char* __restrict__ act1) {
    __shared__ float ws[27 * 64];
    for (int e = threadIdx.x; e < 1728; e += 256) {
        int oc = e / 27, j = e % 27;
        ws[j * 64 + oc] = w1[e];
    }
    __syncthreads();
    int t = blockIdx.x * 256 + threadIdx.x;
    int q = t & 3;
    int m = t >> 2;
    int n = m >> 10, h = (m >> 5) & 31, w = m & 31;
    float xv[27];
#pragma unroll
    for (int ic = 0; ic < 3; ++ic)
#pragma unroll
        for (int kh = 0; kh < 3; ++kh)
#pragma unroll
            for (int kw = 0; kw < 3; ++kw) {
                int r = h + kh - 1, c = w + kw - 1;
                xv[ic * 9 + kh * 3 + kw] =
                    (r >= 0 && r < 32 && c >= 0 && c < 32)
                        ? inp[(n * 3 + ic) * 1024 + r * 32 + c] : 0.0f;
            }
    float s[16], mem[16];
#pragma unroll
    for (int o = 0; o < 16; ++o) { s[o] = 0.f; mem[o] = 0.f; }
#pragma unroll
    for (int j = 0; j < 27; ++j) {
        float x = xv[j];
        const float* wr = &ws[j * 64 + q * 16];
#pragma unroll
        for (int o = 0; o < 16; ++o) s[o] += wr[o] * x;
    }
    const size_t dbase = (((size_t)h + 1) * 34 + (w + 1)) * 64 + q * 16;
    for (int st = 0; st < 10; ++st) {
        unsigned r[4];
#pragma unroll
        for (int g = 0; g < 4; ++g) {
            unsigned acc = 0;
#pragma unroll
            for (int e = 0; e < 4; ++e) {
                int o = g * 4 + e;
                mem[o] = 0.05f * mem[o] + 0.95f * s[o];
                unsigned b = (mem[o] > 1.f) ? 1u : 0u;
                mem[o] -= (float)b;
                acc |= b << (8 * e);
            }
            r[g] = acc;
        }
        size_t d = ((size_t)(st * 128 + n) * 34 * 34) * 64 + dbase;
        *(uint4*)&act1[d] = (uint4){r[0], r[1], r[2], r[3]};
    }
}

// --------------------------------------------------- i8 implicit-GEMM conv --
// Pipelined: 3-buffer sB, one barrier/unit, counted vmcnt (T3/T4), setprio.
template <int H, int W, int IC, int OC, int NI, int MR, int EPI>
__global__ __launch_bounds__(256) void convi8_k(const char* __restrict__ act,
                                                const char* __restrict__ wq,
                                                char* __restrict__ outs,
                                                float scale) {
    constexpr int PW = W + 2, PHR = MR + 2;
    constexpr int MBLK = NI * MR * W;
    constexpr int NPIX = NI * PHR * PW;
    constexpr int ACH = NPIX * 4;
    constexpr int HR = (ACH + 255) / 256;
    constexpr int SLABS = IC / 64;
    constexpr int OCT = OC / 64;
    constexpr int U = SLABS * 9;
    constexpr int LHW = ilog2(H * W), LW2 = ilog2(W), LMW = ilog2(MR * W);
    static_assert(MBLK == 128, "tile mapping");

    __shared__ __align__(16) char sA[NPIX * 64];
    __shared__ __align__(16) char sB[3][12288];

    const int tid = threadIdx.x, lane = tid & 63;
    const int wid = tid >> 6, wm = wid >> 1, wn = wid & 1;
    const int b = blockIdx.x, oct = blockIdx.y;
    const int oc0 = oct * 64;
    const int m0 = b * MBLK;
    constexpr int TPI = (NI == 1) ? (H / MR) : 1;
    const int n0 = (NI == 1) ? (b / TPI) : (b * NI);
    const int h0 = (NI == 1) ? (b % TPI) * MR : 0;

    int asrc[HR]; bool apred[HR];
#pragma unroll
    for (int r = 0; r < HR; ++r) {
        int i = r * 256 + tid;
        apred[r] = (i < ACH);
        int ii = apred[r] ? i : 0;
        int c = ii / NPIX, pix = ii % NPIX;
        int pc = pix % PW, t2 = pix / PW;
        int hp = t2 % PHR, img = t2 / PHR;
        asrc[r] = (((n0 + img) * (H + 2) + h0 + hp) * PW + pc) * IC + c * 16;
    }
    int apix[4];
#pragma unroll
    for (int am = 0; am < 4; ++am) {
        int p = wm * 64 + am * 16 + (lane & 15);
        int img = p >> LMW;
        int pi = p & ((MR * W) - 1);
        int h = pi >> LW2;
        apix[am] = (img * PHR + h) * PW + (pi & (W - 1));
    }
    const int cA = lane >> 4;

    int32x4 acc[3][4][2];
#pragma unroll
    for (int s = 0; s < 3; ++s)
#pragma unroll
        for (int a = 0; a < 4; ++a)
#pragma unroll
            for (int bn = 0; bn < 2; ++bn) acc[s][a][bn] = (int32x4){0, 0, 0, 0};

    const size_t wqoct = (size_t)oct * 12288;

    auto stage_B = [&](int u_) {
        const char* wsrc = wq + (size_t)u_ * (OCT * 12288) + wqoct + tid * 16;
        char* d = sB[u_ % 3] + tid * 16;
        gl_lds16(wsrc, d);
        gl_lds16(wsrc + 4096, d + 4096);
        gl_lds16(wsrc + 8192, d + 8192);
    };
    auto stage_A = [&](int sl_) {
#pragma unroll
        for (int r = 0; r < HR; ++r)
            if (apred[r]) gl_lds16(act + asrc[r] + sl_ * 64, sA + (r * 256 + tid) * 16);
    };

    // prologue: A(slab0), B(0), B(1)
    stage_A(0);
    stage_B(0);
    stage_B(1);

    for (int u = 0; u < U; ++u) {
        const int q = u - (u / 9) * 9;
        // wait: B(u) (and A at slab starts) landed; B(u+1) may stay in flight
        if (q == 0) asm volatile("s_waitcnt vmcnt(0)" ::: "memory");
        else        asm volatile("s_waitcnt vmcnt(3)" ::: "memory");
        __builtin_amdgcn_s_barrier();
        asm volatile("" ::: "memory");
        if (u + 2 < U) stage_B(u + 2);   // safe: all waves finished compute(u-1)

        const int qr = q / 3, qc = q - qr * 3;
        int32x4 af[4];
#pragma unroll
        for (int am = 0; am < 4; ++am) {
            int pix = apix[am] + qr * PW + qc;
            af[am] = *(const int32x4*)&sA[(cA * NPIX + pix) * 16];
        }
        const char* bbase = sB[u % 3];
        __builtin_amdgcn_s_setprio(1);
#pragma unroll
        for (int s = 0; s < 3; ++s)
#pragma unroll
            for (int bn = 0; bn < 2; ++bn) {
                int R = s * 64 + wn * 32 + bn * 16 + (lane & 15);
                int32x4 bf = *(const int32x4*)&bbase[(cA * 192 + R) * 16];
#pragma unroll
                for (int am = 0; am < 4; ++am)
                    acc[s][am][bn] = __builtin_amdgcn_mfma_i32_16x16x64_i8(
                        af[am], bf, acc[s][am][bn], 0, 0, 0);
            }
        __builtin_amdgcn_s_setprio(0);

        if (q == 8 && u + 1 < U) {       // slab boundary: restage halo
            asm volatile("s_waitcnt lgkmcnt(0)" ::: "memory");
            __builtin_amdgcn_s_barrier();
            asm volatile("" ::: "memory");
            stage_A(u / 9 + 1);
        }
    }

#pragma unroll
    for (int am = 0; am < 4; ++am)
#pragma unroll
        for (int bn = 0; bn < 2; ++bn)
#pragma unroll
            for (int rr = 0; rr < 4; ++rr) {
                int rl = wm * 64 + am * 16 + (lane >> 4) * 4 + rr;
                int col = oc0 + wn * 32 + bn * 16 + (lane & 15);
                int m = m0 + rl;
                float v = (float)((65536.0 * (double)acc[0][am][bn][rr]
                                 + 256.0 * (double)acc[1][am][bn][rr]
                                 + (double)acc[2][am][bn][rr]) * (double)scale);
                char sp = (v > 1.0f) ? (char)1 : (char)0;
                if (EPI == 1) {
                    int n = m >> LHW, h = (m >> LW2) & (H - 1), w = m & (W - 1);
                    outs[((size_t)(n * (H + 2) + h + 1) * PW + (w + 1)) * OC + col] = sp;
                } else {
                    outs[(size_t)m * OC + col] = sp;
                }
            }
}

// ------------------------------------------------------------- i8 pool ----
template <int C, int HI>
__global__ void pool_i8_k(const char* __restrict__ in, char* __restrict__ out) {
    constexpr int HO = HI / 2, C16 = C / 16;
    constexpr int TOT = 1280 * HO * HO * C16;
    int idx = blockIdx.x * 256 + threadIdx.x;
    if (idx >= TOT) return;
    int c16 = idx % C16;
    int t = idx / C16;
    int w = t % HO; t /= HO;
    int h = t % HO;
    int n = t / HO;
    const char* p = in + ((size_t)(n * HI + 2 * h) * HI + 2 * w) * C + c16 * 16;
    uint4 a0 = *(const uint4*)p;
    uint4 a1 = *(const uint4*)(p + C);
    uint4 a2 = *(const uint4*)(p + (size_t)HI * C);
    uint4 a3 = *(const uint4*)(p + (size_t)HI * C + C);
    uint4 r;
    r.x = a0.x + a1.x + a2.x + a3.x;
    r.y = a0.y + a1.y + a2.y + a3.y;
    r.z = a0.z + a1.z + a2.z + a3.z;
    r.w = a0.w + a1.w + a2.w + a3.w;
    *(uint4*)&out[((size_t)(n * (HO + 2) + h + 1) * (HO + 2) + (w + 1)) * C + c16 * 16] = r;
}

__global__ void pool3q_k(const char* __restrict__ in, char* __restrict__ out) {
    int idx = blockIdx.x * 256 + threadIdx.x;   // 327680
    if (idx >= 327680) return;
    int c16 = idx & 15;
    int t = idx >> 4;
    int wo = t & 3, ho = (t >> 2) & 3, n = t >> 4;
    const char* p = in + ((size_t)(n * 8 + 2 * ho) * 8 + 2 * wo) * 256 + c16 * 16;
    uint4 a0 = *(const uint4*)p;
    uint4 a1 = *(const uint4*)(p + 256);
    uint4 a2 = *(const uint4*)(p + 2048);
    uint4 a3 = *(const uint4*)(p + 2048 + 256);
    uint4 r;
    r.x = a0.x + a1.x + a2.x + a3.x;
    r.y = a0.y + a1.y + a2.y + a3.y;
    r.z = a0.z + a1.z + a2.z + a3.z;
    r.w = a0.w + a1.w + a2.w + a3.w;
    *(uint4*)&out[((size_t)(n * 16 + ho * 4 + wo) * 16 + c16) * 16] = r;
}

// ----------------------------------------------------------- fc1 i8 GEMM ----
__global__ __launch_bounds__(256) void fc1i8_k(const char* __restrict__ A,
                                               const char* __restrict__ wq,
                                               float* __restrict__ part) {
    __shared__ __align__(16) char sA[2][8192];
    __shared__ __align__(16) char sB[2][12288];
    const int tid = threadIdx.x, lane = tid & 63;
    const int wid = tid >> 6, wm = wid >> 1, wn = wid & 1;
    const int m0 = blockIdx.x * 128, oct = blockIdx.y, kt = blockIdx.z;

    int32x4 acc[3][4][2];
#pragma unroll
    for (int s = 0; s < 3; ++s)
#pragma unroll
        for (int a = 0; a < 4; ++a)
#pragma unroll
            for (int bn = 0; bn < 2; ++bn) acc[s][a][bn] = (int32x4){0, 0, 0, 0};

    auto stageA = [&](int sg, int bf_) {
#pragma unroll
        for (int r = 0; r < 2; ++r) {
            int i = r * 256 + tid;
            int c = i >> 7, pix = i & 127;
            gl_lds16(A + (size_t)(m0 + pix) * 4096 + sg * 64 + c * 16,
                     sA[bf_] + (size_t)i * 16);
        }
    };
    auto stageB = [&](int sg, int bf_) {
        const char* src = wq + ((size_t)(sg * 16 + oct)) * 12288 + tid * 16;
#pragma unroll
        for (int r = 0; r < 3; ++r)
            gl_lds16(src + r * 4096, sB[bf_] + (r * 256 + tid) * 16);
    };

    int buf = 0;
    stageA(kt * 32, 0);
    stageB(kt * 32, 0);
    __syncthreads();
    const int cA = lane >> 4;
    for (int sl = 0; sl < 32; ++sl) {
        int sg = kt * 32 + sl;
        if (sl < 31) { stageA(sg + 1, buf ^ 1); stageB(sg + 1, buf ^ 1); }
        int32x4 af[4];
#pragma unroll
        for (int am = 0; am < 4; ++am)
            af[am] = *(const int32x4*)&sA[buf][(cA * 128 + wm * 64 + am * 16 + (lane & 15)) * 16];
#pragma unroll
        for (int s = 0; s < 3; ++s)
#pragma unroll
            for (int bn = 0; bn < 2; ++bn) {
                int R = s * 64 + wn * 32 + bn * 16 + (lane & 15);
                int32x4 bf = *(const int32x4*)&sB[buf][(cA * 192 + R) * 16];
#pragma unroll
                for (int am = 0; am < 4; ++am)
                    acc[s][am][bn] = __builtin_amdgcn_mfma_i32_16x16x64_i8(
                        af[am], bf, acc[s][am][bn], 0, 0, 0);
            }
        if (sl < 31) { __syncthreads(); buf ^= 1; }
    }
#pragma unroll
    for (int am = 0; am < 4; ++am)
#pragma unroll
        for (int bn = 0; bn < 2; ++bn)
#pragma unroll
            for (int rr = 0; rr < 4; ++rr) {
                int row = m0 + wm * 64 + am * 16 + (lane >> 4) * 4 + rr;
                int col = oct * 64 + wn * 32 + bn * 16 + (lane & 15);
                float v = (float)((65536.0 * (double)acc[0][am][bn][rr]
                                 + 256.0 * (double)acc[1][am][bn][rr]
                                 + (double)acc[2][am][bn][rr]) * SC23);
                part[((size_t)kt * 1280 + row) * 1024 + col] = v;
            }
}

__global__ void fc1lif_k(const float* __restrict__ part, ushort* __restrict__ sbuf) {
    int idx = blockIdx.x * 256 + threadIdx.x;   // 131072
    int n = idx >> 10, j = idx & 1023;
    float m = 0.f;
    for (int t = 0; t < 10; ++t) {
        size_t row = (size_t)(t * 128 + n) * 1024 + j;
        float y = part[row] + part[1310720 + row];
        m = 0.05f * m + 0.95f * y;
        float sp = (m > 1.f) ? 1.f : 0.f;
        m -= sp;
        sbuf[row] = sp > 0.f ? (ushort)0x3F80 : (ushort)0;
    }
}

__global__ __launch_bounds__(256) void fc2o_k(const ushort* __restrict__ S,
                                              const float* __restrict__ W2,
                                              float* __restrict__ out) {
    __shared__ float wsh[10 * 1024];
    __shared__ float red[10][256];
    int n = blockIdx.x, tid = threadIdx.x;
    for (int e = tid; e < 10240; e += 256) wsh[e] = W2[e];
    __syncthreads();
    float accv = 0.f;
    for (int t = 0; t < 10; ++t) {
        const ushort* sp = S + ((size_t)(t * 128 + n)) * 1024 + tid * 4;
        float s0 = bf2f(sp[0]), s1 = bf2f(sp[1]), s2 = bf2f(sp[2]), s3 = bf2f(sp[3]);
#pragma unroll
        for (int o = 0; o < 10; ++o) {
            const float* w = &wsh[o * 1024 + tid * 4];
            red[o][tid] = s0 * w[0] + s1 * w[1] + s2 * w[2] + s3 * w[3];
        }
        __syncthreads();
        for (int off = 128; off >= 1; off >>= 1) {
            if (tid < off) {
#pragma unroll
                for (int o = 0; o < 10; ++o) red[o][tid] += red[o][tid + off];
            }
            __syncthreads();
        }
        if (tid < 10) accv += red[tid][0];
        __syncthreads();
    }
    if (tid < 10) out[n * 10 + tid] = accv * 0.1f;
}

// ---------------------------------------------------------------------------
extern "C" void kernel_launch(void* const* d_in, const int* in_sizes, int n_in,
                              void* d_out, int out_size, void* d_ws, size_t ws_size,
                              hipStream_t stream) {
    const float* inp  = (const float*)d_in[0];
    const float* w1   = (const float*)d_in[1];
    const float* w2   = (const float*)d_in[2];
    const float* w3   = (const float*)d_in[3];
    const float* w4   = (const float*)d_in[4];
    const float* w5   = (const float*)d_in[5];
    const float* w6   = (const float*)d_in[6];
    const float* w7   = (const float*)d_in[7];
    const float* fc1w = (const float*)d_in[8];
    const float* fc2w = (const float*)d_in[9];
    float* out = (float*)d_out;

    char* base = (char*)d_ws;
    char* arenaA = base;                          // 94,679,040 B
    char* arenaB = base + 94679040;               // 83,886,080 B
    size_t o = 94679040 + 83886080;
    auto alloc = [&](size_t bytes) { void* p = base + o; o += (bytes + 255) & ~(size_t)255; return p; };
    char*   wq2  = (char*)alloc(110592);
    char*   wq3  = (char*)alloc(221184);
    char*   wq4  = (char*)alloc(442368);
    char*   wq5  = (char*)alloc(884736);
    char*   wq6  = (char*)alloc(1769472);
    char*   wq7  = (char*)alloc(1769472);
    char*   wqf1 = (char*)alloc(12582912);
    ushort* sbuf = (ushort*)alloc(2621440);
    (void)ws_size;

    char*  act1  = arenaA;                        // [1280][34][34][64]
    char*  c2out = arenaB;                        // [1280][32][32][64]
    char*  act2  = arenaA;                        // [1280][18][18][64]
    char*  c3out = arenaB;                        // [1280][18][18][128]
    char*  c4out = arenaA;                        // [1280][16][16][128]
    char*  act3  = arenaA + 41943040;             // [1280][10][10][128]
    char*  c5out = arenaB;                        // [1280][10][10][256]
    char*  c6out = arenaB + 33554432;             // [1280][10][10][256]
    char*  c7out = arenaA;                        // [1280][8][8][256]
    char*  afc1  = arenaA + 20971520;             // [1280][4096] i8
    float* part  = (float*)(arenaA + 26214400);   // [2][1280][1024] f32

    prep_convw_i8_k<64, 64>  <<<(36864 + 255) / 256, 256, 0, stream>>>(w2, wq2);
    prep_convw_i8_k<64, 128> <<<(73728 + 255) / 256, 256, 0, stream>>>(w3, wq3);
    prep_convw_i8_k<128, 128><<<(147456 + 255) / 256, 256, 0, stream>>>(w4, wq4);
    prep_convw_i8_k<128, 256><<<(294912 + 255) / 256, 256, 0, stream>>>(w5, wq5);
    prep_convw_i8_k<256, 256><<<(589824 + 255) / 256, 256, 0, stream>>>(w6, wq6);
    prep_convw_i8_k<256, 256><<<(589824 + 255) / 256, 256, 0, stream>>>(w7, wq7);
    prep_fc1w_i8_k<<<(4194304 + 255) / 256, 256, 0, stream>>>(fc1w, wqf1);

    halo0_k<32, 64><<<(1280 * 132 * 4 + 255) / 256, 256, 0, stream>>>(act1);
    conv1lif_k<<<2048, 256, 0, stream>>>(inp, w1, act1);

    convi8_k<32, 32, 64, 64, 1, 4, 0>
        <<<dim3(10240, 1), 256, 0, stream>>>(act1, wq2, c2out, (float)SC21);
    halo0_k<16, 64><<<(1280 * 68 * 4 + 255) / 256, 256, 0, stream>>>(act2);
    pool_i8_k<64, 32><<<(1280 * 256 * 4 + 255) / 256, 256, 0, stream>>>(c2out, act2);

    halo0_k<16, 128><<<(1280 * 68 * 8 + 255) / 256, 256, 0, stream>>>(c3out);
    convi8_k<16, 16, 64, 128, 1, 8, 1>
        <<<dim3(2560, 2), 256, 0, stream>>>(act2, wq3, c3out, (float)SC23);
    convi8_k<16, 16, 128, 128, 1, 8, 0>
        <<<dim3(2560, 2), 256, 0, stream>>>(c3out, wq4, c4out, (float)SC21);
    halo0_k<8, 128><<<(1280 * 36 * 8 + 255) / 256, 256, 0, stream>>>(act3);
    pool_i8_k<128, 16><<<(1280 * 64 * 8 + 255) / 256, 256, 0, stream>>>(c4out, act3);

    halo0_k<8, 256><<<(1280 * 36 * 16 + 255) / 256, 256, 0, stream>>>(c5out);
    convi8_k<8, 8, 128, 256, 2, 8, 1>
        <<<dim3(640, 4), 256, 0, stream>>>(act3, wq5, c5out, (float)SC23);
    halo0_k<8, 256><<<(1280 * 36 * 16 + 255) / 256, 256, 0, stream>>>(c6out);
    convi8_k<8, 8, 256, 256, 2, 8, 1>
        <<<dim3(640, 4), 256, 0, stream>>>(c5out, wq6, c6out, (float)SC21);
    convi8_k<8, 8, 256, 256, 2, 8, 0>
        <<<dim3(640, 4), 256, 0, stream>>>(c6out, wq7, c7out, (float)SC21);

    pool3q_k<<<(327680 + 255) / 256, 256, 0, stream>>>(c7out, afc1);

    fc1i8_k<<<dim3(10, 16, 2), 256, 0, stream>>>(afc1, wqf1, part);
    fc1lif_k<<<512, 256, 0, stream>>>(part, sbuf);
    fc2o_k<<<128, 256, 0, stream>>>(sbuf, fc2w, out);
}